// Round 1
// baseline (10730.795 us; speedup 1.0000x reference)
//
#include <hip/hip_runtime.h>
#include <math.h>

#define HID 64
#define HEADS 4
#define HDIM 16
#define LAYERS 3
#define NGRAPH 128

__device__ __forceinline__ float gelu_f(float x) {
    return 0.5f * x * (1.0f + erff(x * 0.70710678118654752440f));
}

// monotonic float<->uint mapping for atomicMax on floats
__device__ __forceinline__ unsigned int f2mono(float f) {
    unsigned int u = __float_as_uint(f);
    return (u & 0x80000000u) ? ~u : (u | 0x80000000u);
}
__device__ __forceinline__ float mono2f(unsigned int u) {
    return (u & 0x80000000u) ? __uint_as_float(u ^ 0x80000000u)
                             : __uint_as_float(~u);
}

__device__ __forceinline__ float wave_sum64(float v) {
#pragma unroll
    for (int o = 32; o > 0; o >>= 1) v += __shfl_xor(v, o, 64);
    return v;
}

// h = LN(gelu(x @ in_W + in_b))   one wave per node
__global__ __launch_bounds__(256) void k_input(
    const float* __restrict__ x, const float* __restrict__ W,
    const float* __restrict__ b, const float* __restrict__ g,
    const float* __restrict__ be, float* __restrict__ h, int n) {
    int lane = threadIdx.x & 63;
    int node = blockIdx.x * 4 + (threadIdx.x >> 6);
    if (node >= n) return;
    const float* xr = x + (size_t)node * 32;
    float acc = b[lane];
#pragma unroll
    for (int i = 0; i < 32; i++) acc = fmaf(xr[i], W[i * 64 + lane], acc);
    acc = gelu_f(acc);
    float mu = wave_sum64(acc) * (1.0f / 64.0f);
    float d = acc - mu;
    float var = wave_sum64(d * d) * (1.0f / 64.0f);
    h[(size_t)node * 64 + lane] = d * rsqrtf(var + 1e-5f) * g[lane] + be[lane];
}

// q,k,v projections; one wave per node, lane = output column
__global__ __launch_bounds__(256) void k_qkv(
    const float* __restrict__ h, const float* __restrict__ W,
    const float* __restrict__ bias, float* __restrict__ q,
    float* __restrict__ k, float* __restrict__ v, int n) {
    int lane = threadIdx.x & 63;
    int node = blockIdx.x * 4 + (threadIdx.x >> 6);
    if (node >= n) return;
    const float* hr = h + (size_t)node * 64;
    const float* Wq = W;
    const float* Wk = W + 4096;
    const float* Wv = W + 8192;
    float aq = bias[lane], ak = bias[64 + lane], av = bias[128 + lane];
#pragma unroll 8
    for (int i = 0; i < 64; i++) {
        float hv = hr[i];
        aq = fmaf(hv, Wq[i * 64 + lane], aq);
        ak = fmaf(hv, Wk[i * 64 + lane], ak);
        av = fmaf(hv, Wv[i * 64 + lane], av);
    }
    size_t o = (size_t)node * 64 + lane;
    q[o] = aq;
    k[o] = ak;
    v[o] = av;
}

// per (edge, head): alpha = scale * dot(q[dst], k[src] + ea*W_edge); segment max
__global__ __launch_bounds__(256) void k_alpha(
    const float* __restrict__ q, const float* __restrict__ k,
    const int* __restrict__ src, const int* __restrict__ dst,
    const float* __restrict__ ea, const float* __restrict__ We,
    float* __restrict__ alpha, unsigned int* __restrict__ amax, int E) {
    int t = blockIdx.x * 256 + threadIdx.x;
    if (t >= E * 4) return;
    int e = t >> 2, hh = t & 3;
    int s = src[e], d = dst[e];
    float a = ea[e];
    const float4* qp = (const float4*)(q + (size_t)d * 64 + hh * 16);
    const float4* kp = (const float4*)(k + (size_t)s * 64 + hh * 16);
    const float4* wp = (const float4*)(We + hh * 16);
    float sum = 0.f;
#pragma unroll
    for (int i = 0; i < 4; i++) {
        float4 qv = qp[i], kv = kp[i], wv = wp[i];
        sum += qv.x * fmaf(a, wv.x, kv.x) + qv.y * fmaf(a, wv.y, kv.y) +
               qv.z * fmaf(a, wv.z, kv.z) + qv.w * fmaf(a, wv.w, kv.w);
    }
    sum *= 0.25f;  // 1/sqrt(16)
    alpha[t] = sum;
    atomicMax(amax + (size_t)d * 4 + hh, f2mono(sum));
}

// per (edge, head): ex = exp(alpha - amax[dst]); den += ex; acc += ex*(v[src]+e)
__global__ __launch_bounds__(256) void k_accum(
    const float* __restrict__ v, const int* __restrict__ src,
    const int* __restrict__ dst, const float* __restrict__ ea,
    const float* __restrict__ We, const float* __restrict__ alpha,
    const unsigned int* __restrict__ amax, float* __restrict__ den,
    float* __restrict__ acc, int E) {
    int t = blockIdx.x * 256 + threadIdx.x;
    if (t >= E * 4) return;
    int e = t >> 2, hh = t & 3;
    int s = src[e], d = dst[e];
    float am = mono2f(amax[(size_t)d * 4 + hh]);
    float ex = expf(alpha[t] - am);
    atomicAdd(den + (size_t)d * 4 + hh, ex);
    float a = ea[e];
    const float4* vp = (const float4*)(v + (size_t)s * 64 + hh * 16);
    const float4* wp = (const float4*)(We + hh * 16);
    float* ap = acc + (size_t)d * 64 + hh * 16;
#pragma unroll
    for (int i = 0; i < 4; i++) {
        float4 vv = vp[i], wv = wp[i];
        atomicAdd(ap + i * 4 + 0, ex * fmaf(a, wv.x, vv.x));
        atomicAdd(ap + i * 4 + 1, ex * fmaf(a, wv.y, vv.y));
        atomicAdd(ap + i * 4 + 2, ex * fmaf(a, wv.z, vv.z));
        atomicAdd(ap + i * 4 + 3, ex * fmaf(a, wv.w, vv.w));
    }
}

// per node: out=acc/den; x_r=h@W_skip+b; beta gate; h = LN(gelu(out2)+res)
__global__ __launch_bounds__(256) void k_node(
    float* __restrict__ h, const float* __restrict__ acc,
    const float* __restrict__ den, const float* __restrict__ Ws,
    const float* __restrict__ bs, const float* __restrict__ Wb,
    const float* __restrict__ lg, const float* __restrict__ lb, int n) {
    int lane = threadIdx.x & 63;
    int node = blockIdx.x * 4 + (threadIdx.x >> 6);
    if (node >= n) return;
    float* hr = h + (size_t)node * 64;
    float res = hr[lane];
    float xr = bs[lane];
#pragma unroll 8
    for (int i = 0; i < 64; i++) xr = fmaf(hr[i], Ws[i * 64 + lane], xr);
    float o = acc[(size_t)node * 64 + lane] /
              (den[(size_t)node * 4 + (lane >> 4)] + 1e-16f);
    float cb = o * Wb[lane] + xr * Wb[64 + lane] + (o - xr) * Wb[128 + lane];
    cb = wave_sum64(cb);
    float beta = 1.0f / (1.0f + expf(-cb));
    float o2 = fmaf(beta, xr - o, o);  // beta*xr + (1-beta)*o
    float gv = gelu_f(o2) + res;
    float mu = wave_sum64(gv) * (1.0f / 64.0f);
    float dd = gv - mu;
    float var = wave_sum64(dd * dd) * (1.0f / 64.0f);
    hr[lane] = dd * rsqrtf(var + 1e-5f) * lg[lane] + lb[lane];
}

// graph pooling: sum + max + count via atomics
__global__ __launch_bounds__(256) void k_pool(
    const float* __restrict__ h, const int* __restrict__ batch,
    float* __restrict__ gsum, unsigned int* __restrict__ gmax,
    float* __restrict__ cnt, int n) {
    int t = blockIdx.x * 256 + threadIdx.x;
    if (t >= n * 64) return;
    int node = t >> 6, c = t & 63;
    int g = batch[node];
    float v = h[t];
    atomicAdd(gsum + g * 64 + c, v);
    atomicMax(gmax + g * 64 + c, f2mono(v));
    if (c == 0) atomicAdd(cnt + g, 1.0f);
}

// final MLP head: one block (64 threads) per graph
__global__ void k_final(const float* __restrict__ gsum,
                        const unsigned int* __restrict__ gmax,
                        const float* __restrict__ cnt,
                        const float* __restrict__ W1, const float* __restrict__ b1,
                        const float* __restrict__ W2, const float* __restrict__ b2,
                        const float* __restrict__ W3, const float* __restrict__ b3,
                        float* __restrict__ out) {
    int g = blockIdx.x;
    int lane = threadIdx.x;  // 64 threads
    __shared__ float rep[128];
    __shared__ float t1[64];
    __shared__ float t2[32];
    float c = fmaxf(cnt[g], 1.0f);
    rep[lane] = gsum[g * 64 + lane] / c;
    rep[64 + lane] = mono2f(gmax[g * 64 + lane]);
    __syncthreads();
    float a = b1[lane];
#pragma unroll 8
    for (int i = 0; i < 128; i++) a = fmaf(rep[i], W1[i * 64 + lane], a);
    t1[lane] = gelu_f(a);
    __syncthreads();
    if (lane < 32) {
        float a2 = b2[lane];
#pragma unroll 8
        for (int i = 0; i < 64; i++) a2 = fmaf(t1[i], W2[i * 32 + lane], a2);
        t2[lane] = gelu_f(a2);
    }
    __syncthreads();
    if (lane < 32) {
        float p = t2[lane] * W3[lane];
#pragma unroll
        for (int o = 16; o > 0; o >>= 1) p += __shfl_xor(p, o, 64);
        if (lane == 0) out[g] = p + b3[0];
    }
}

extern "C" void kernel_launch(void* const* d_in, const int* in_sizes, int n_in,
                              void* d_out, int out_size, void* d_ws,
                              size_t ws_size, hipStream_t stream) {
    const float* x      = (const float*)d_in[0];
    const int*   eidx   = (const int*)d_in[1];
    const float* ea     = (const float*)d_in[2];
    const int*   batch  = (const int*)d_in[3];
    const float* in_W   = (const float*)d_in[4];
    const float* in_b   = (const float*)d_in[5];
    const float* in_lng = (const float*)d_in[6];
    const float* in_lnb = (const float*)d_in[7];
    const float* W_qkv  = (const float*)d_in[8];
    const float* b_qkv  = (const float*)d_in[9];
    const float* W_edge = (const float*)d_in[10];
    const float* W_skip = (const float*)d_in[11];
    const float* b_skip = (const float*)d_in[12];
    const float* W_beta = (const float*)d_in[13];
    const float* ln_g   = (const float*)d_in[14];
    const float* ln_b   = (const float*)d_in[15];
    const float* r1_W   = (const float*)d_in[16];
    const float* r1_b   = (const float*)d_in[17];
    const float* r2_W   = (const float*)d_in[18];
    const float* r2_b   = (const float*)d_in[19];
    const float* r3_W   = (const float*)d_in[20];
    const float* r3_b   = (const float*)d_in[21];

    int n = in_sizes[0] / 32;
    int E = in_sizes[2];
    const int* src = eidx;
    const int* dst = eidx + E;

    char* ws = (char*)d_ws;
    size_t off = 0;
    auto alloc = [&](size_t bytes) -> void* {
        void* p = ws + off;
        off = (off + bytes + 255) & ~(size_t)255;
        return p;
    };
    float* h     = (float*)alloc((size_t)n * 64 * 4);
    float* q     = (float*)alloc((size_t)n * 64 * 4);
    float* k     = (float*)alloc((size_t)n * 64 * 4);
    float* v     = (float*)alloc((size_t)n * 64 * 4);
    float* acc   = (float*)alloc((size_t)n * 64 * 4);
    float* alpha = (float*)alloc((size_t)E * 4 * 4);
    unsigned int* amax = (unsigned int*)alloc((size_t)n * 4 * 4);
    float* den   = (float*)alloc((size_t)n * 4 * 4);
    float* gsum  = (float*)alloc(NGRAPH * 64 * 4);
    unsigned int* gmax = (unsigned int*)alloc(NGRAPH * 64 * 4);
    float* cnt   = (float*)alloc(NGRAPH * 4);

    int nb4 = (n + 3) / 4;
    int eb = (E * 4 + 255) / 256;

    k_input<<<nb4, 256, 0, stream>>>(x, in_W, in_b, in_lng, in_lnb, h, n);

    for (int l = 0; l < LAYERS; l++) {
        k_qkv<<<nb4, 256, 0, stream>>>(h, W_qkv + (size_t)l * 3 * 4096,
                                       b_qkv + (size_t)l * 192, q, k, v, n);
        hipMemsetAsync(amax, 0, (size_t)n * 4 * 4, stream);
        hipMemsetAsync(den, 0, (size_t)n * 4 * 4, stream);
        hipMemsetAsync(acc, 0, (size_t)n * 64 * 4, stream);
        k_alpha<<<eb, 256, 0, stream>>>(q, k, src, dst, ea, W_edge + l * 64,
                                        alpha, amax, E);
        k_accum<<<eb, 256, 0, stream>>>(v, src, dst, ea, W_edge + l * 64,
                                        alpha, amax, den, acc, E);
        k_node<<<nb4, 256, 0, stream>>>(h, acc, den, W_skip + (size_t)l * 4096,
                                        b_skip + l * 64, W_beta + l * 192,
                                        ln_g + l * 64, ln_b + l * 64, n);
    }

    hipMemsetAsync(gsum, 0, NGRAPH * 64 * 4, stream);
    hipMemsetAsync(gmax, 0, NGRAPH * 64 * 4, stream);
    hipMemsetAsync(cnt, 0, NGRAPH * 4, stream);
    k_pool<<<(n * 64 + 255) / 256, 256, 0, stream>>>(h, batch, gsum, gmax, cnt, n);
    k_final<<<NGRAPH, 64, 0, stream>>>(gsum, gmax, cnt, r1_W, r1_b, r2_W, r2_b,
                                       r3_W, r3_b, (float*)d_out);
}

// Round 2
// 963.919 us; speedup vs baseline: 11.1325x; 11.1325x over previous
//
#include <hip/hip_runtime.h>
#include <math.h>
#include <float.h>

#define LAYERS 3
#define NGRAPH 128

__device__ __forceinline__ float gelu_f(float x) {
    return 0.5f * x * (1.0f + erff(x * 0.70710678118654752440f));
}

__device__ __forceinline__ float wave_sum64(float v) {
#pragma unroll
    for (int o = 32; o > 0; o >>= 1) v += __shfl_xor(v, o, 64);
    return v;
}

__device__ __forceinline__ int lbound(const int* __restrict__ a, int n, int key) {
    int lo = 0, hi = n;
    while (lo < hi) {
        int mid = (lo + hi) >> 1;
        if (a[mid] < key) lo = mid + 1; else hi = mid;
    }
    return lo;
}

// ---------------- CSR build ----------------
__global__ __launch_bounds__(256) void k_hist(const int* __restrict__ dst,
                                              int* __restrict__ deg, int E) {
    int e = blockIdx.x * 256 + threadIdx.x;
    if (e < E) atomicAdd(&deg[dst[e]], 1);
}

__global__ __launch_bounds__(256) void k_scan1(const int* __restrict__ deg,
                                               int* __restrict__ excl,
                                               int* __restrict__ bsum, int n) {
    __shared__ int s[256];
    int t = threadIdx.x;
    int i = blockIdx.x * 256 + t;
    int v = (i < n) ? deg[i] : 0;
    s[t] = v;
    __syncthreads();
    for (int off = 1; off < 256; off <<= 1) {
        int a = (t >= off) ? s[t - off] : 0;
        __syncthreads();
        s[t] += a;
        __syncthreads();
    }
    if (i < n) excl[i] = s[t] - v;
    if (t == 255) bsum[blockIdx.x] = s[255];
}

__global__ __launch_bounds__(512) void k_scan2(int* __restrict__ bsum, int nb) {
    __shared__ int s[512];
    int t = threadIdx.x;
    int v = (t < nb) ? bsum[t] : 0;
    s[t] = v;
    __syncthreads();
    for (int off = 1; off < 512; off <<= 1) {
        int a = (t >= off) ? s[t - off] : 0;
        __syncthreads();
        s[t] += a;
        __syncthreads();
    }
    if (t < nb) bsum[t] = s[t] - v;  // exclusive
}

__global__ __launch_bounds__(256) void k_scan3(const int* __restrict__ excl,
                                               const int* __restrict__ bsum,
                                               int* __restrict__ row,
                                               int* __restrict__ cursor,
                                               int n, int E) {
    int i = blockIdx.x * 256 + threadIdx.x;
    if (i < n) {
        int r = excl[i] + bsum[blockIdx.x];
        row[i] = r;
        cursor[i] = r;
    }
    if (blockIdx.x == 0 && threadIdx.x == 0) row[n] = E;
}

__global__ __launch_bounds__(256) void k_scatter(const int* __restrict__ src,
                                                 const int* __restrict__ dst,
                                                 const float* __restrict__ ea,
                                                 int* __restrict__ cursor,
                                                 int* __restrict__ esrc,
                                                 float* __restrict__ eea, int E) {
    int e = blockIdx.x * 256 + threadIdx.x;
    if (e >= E) return;
    int d = dst[e];
    int p = atomicAdd(&cursor[d], 1);
    esrc[p] = src[e];
    eea[p] = ea[e];
}

// ---------------- model ----------------
// h = LN(gelu(x @ in_W + in_b)); one wave per node
__global__ __launch_bounds__(256) void k_input(
    const float* __restrict__ x, const float* __restrict__ W,
    const float* __restrict__ b, const float* __restrict__ g,
    const float* __restrict__ be, float* __restrict__ h, int n) {
    int lane = threadIdx.x & 63;
    int node = blockIdx.x * 4 + (threadIdx.x >> 6);
    if (node >= n) return;
    const float* xr = x + (size_t)node * 32;
    float acc = b[lane];
#pragma unroll
    for (int i = 0; i < 32; i++) acc = fmaf(xr[i], W[i * 64 + lane], acc);
    acc = gelu_f(acc);
    float mu = wave_sum64(acc) * (1.0f / 64.0f);
    float d = acc - mu;
    float var = wave_sum64(d * d) * (1.0f / 64.0f);
    h[(size_t)node * 64 + lane] = d * rsqrtf(var + 1e-5f) * g[lane] + be[lane];
}

// q,k,v projections; 4 nodes per wave (shared W reads), kv interleaved
__global__ __launch_bounds__(256) void k_qkv(
    const float* __restrict__ h, const float* __restrict__ W,
    const float* __restrict__ bias, float* __restrict__ q,
    float* __restrict__ kvout, int n) {
    int lane = threadIdx.x & 63;
    int base = (blockIdx.x * 4 + (threadIdx.x >> 6)) * 4;
    if (base >= n) return;
    const float* Wq = W;
    const float* Wk = W + 4096;
    const float* Wv = W + 8192;
    float hreg[4];
#pragma unroll
    for (int t = 0; t < 4; t++) {
        int nd = min(base + t, n - 1);
        hreg[t] = h[(size_t)nd * 64 + lane];
    }
    float aq[4], ak[4], av[4];
#pragma unroll
    for (int t = 0; t < 4; t++) {
        aq[t] = bias[lane];
        ak[t] = bias[64 + lane];
        av[t] = bias[128 + lane];
    }
    for (int i = 0; i < 64; i++) {
        float wq = Wq[i * 64 + lane], wk = Wk[i * 64 + lane], wv = Wv[i * 64 + lane];
#pragma unroll
        for (int t = 0; t < 4; t++) {
            float hv = __shfl(hreg[t], i);
            aq[t] = fmaf(hv, wq, aq[t]);
            ak[t] = fmaf(hv, wk, ak[t]);
            av[t] = fmaf(hv, wv, av[t]);
        }
    }
#pragma unroll
    for (int t = 0; t < 4; t++) {
        int nd = base + t;
        if (nd < n) {
            q[(size_t)nd * 64 + lane] = aq[t];
            kvout[(size_t)nd * 128 + lane] = ak[t];
            kvout[(size_t)nd * 128 + 64 + lane] = av[t];
        }
    }
}

// per-node online-softmax attention over CSR in-edges; one wave per node; no atomics
__global__ __launch_bounds__(256) void k_attn(
    const float* __restrict__ q, const float* __restrict__ kv,
    const int* __restrict__ row, const int* __restrict__ esrc,
    const float* __restrict__ eea, const float* __restrict__ We,
    float* __restrict__ out, int n) {
    int lane = threadIdx.x & 63;
    int node = blockIdx.x * 4 + (threadIdx.x >> 6);
    if (node >= n) return;
    float we = We[lane];
    float qv = q[(size_t)node * 64 + lane];
    int beg = row[node], end = row[node + 1];
    float m = -3.402823466e38f, den = 0.f, acc = 0.f;
    for (int cb = beg; cb < end; cb += 64) {
        int cnt = min(64, end - cb);
        int sv = 0;
        float av = 0.f;
        if (lane < cnt) {
            sv = esrc[cb + lane];
            av = eea[cb + lane];
        }
        for (int jj = 0; jj < cnt; jj++) {
            int s = __shfl(sv, jj);
            float a = __shfl(av, jj);
            const float* kp = kv + (size_t)s * 128;
            float kval = kp[lane];
            float vval = kp[64 + lane];
            float val = qv * fmaf(a, we, kval);
            val += __shfl_xor(val, 1);
            val += __shfl_xor(val, 2);
            val += __shfl_xor(val, 4);
            val += __shfl_xor(val, 8);
            float alpha = val * 0.25f;  // * 1/sqrt(16)
            float nm = fmaxf(m, alpha);
            float sc = __expf(m - nm);
            float ex = __expf(alpha - nm);
            den = den * sc + ex;
            acc = acc * sc + ex * fmaf(a, we, vval);
            m = nm;
        }
    }
    out[(size_t)node * 64 + lane] = acc / (den + 1e-16f);
}

// per node: x_r = h@W_skip+b; beta gate; h = LN(gelu(out2)+res); 4 nodes/wave
__global__ __launch_bounds__(256) void k_node(
    float* __restrict__ h, const float* __restrict__ o_in,
    const float* __restrict__ Ws, const float* __restrict__ bs,
    const float* __restrict__ Wb, const float* __restrict__ lg,
    const float* __restrict__ lb, int n) {
    int lane = threadIdx.x & 63;
    int base = (blockIdx.x * 4 + (threadIdx.x >> 6)) * 4;
    if (base >= n) return;
    float hreg[4], xr[4];
#pragma unroll
    for (int t = 0; t < 4; t++) {
        int nd = min(base + t, n - 1);
        hreg[t] = h[(size_t)nd * 64 + lane];
        xr[t] = bs[lane];
    }
    for (int i = 0; i < 64; i++) {
        float w = Ws[i * 64 + lane];
#pragma unroll
        for (int t = 0; t < 4; t++) xr[t] = fmaf(__shfl(hreg[t], i), w, xr[t]);
    }
    float wb0 = Wb[lane], wb1 = Wb[64 + lane], wb2 = Wb[128 + lane];
    float lgv = lg[lane], lbv = lb[lane];
#pragma unroll
    for (int t = 0; t < 4; t++) {
        int nd = base + t;
        if (nd >= n) break;
        float o = o_in[(size_t)nd * 64 + lane];
        float cb = o * wb0 + xr[t] * wb1 + (o - xr[t]) * wb2;
        cb = wave_sum64(cb);
        float beta = 1.0f / (1.0f + expf(-cb));
        float o2 = fmaf(beta, xr[t] - o, o);
        float gv = gelu_f(o2) + hreg[t];
        float mu = wave_sum64(gv) * (1.0f / 64.0f);
        float dd = gv - mu;
        float var = wave_sum64(dd * dd) * (1.0f / 64.0f);
        h[(size_t)nd * 64 + lane] = dd * rsqrtf(var + 1e-5f) * lgv + lbv;
    }
}

// pooling: one block per graph over sorted batch; no atomics
__global__ __launch_bounds__(256) void k_pool2(const float* __restrict__ h,
                                               const int* __restrict__ batch,
                                               float* __restrict__ rep, int n) {
    int g = blockIdx.x;
    int lane = threadIdx.x & 63, wid = threadIdx.x >> 6;
    int start = lbound(batch, n, g), end = lbound(batch, n, g + 1);
    float s = 0.f, mx = -FLT_MAX;
    for (int i = start + wid; i < end; i += 4) {
        float v = h[(size_t)i * 64 + lane];
        s += v;
        mx = fmaxf(mx, v);
    }
    __shared__ float ssum[4][64], smax[4][64];
    ssum[wid][lane] = s;
    smax[wid][lane] = mx;
    __syncthreads();
    if (wid == 0) {
#pragma unroll
        for (int w = 1; w < 4; w++) {
            s += ssum[w][lane];
            mx = fmaxf(mx, smax[w][lane]);
        }
        float c = fmaxf((float)(end - start), 1.0f);
        rep[g * 128 + lane] = s / c;
        rep[g * 128 + 64 + lane] = mx;
    }
}

// final MLP head: one block (64 threads) per graph
__global__ void k_final(const float* __restrict__ rep,
                        const float* __restrict__ W1, const float* __restrict__ b1,
                        const float* __restrict__ W2, const float* __restrict__ b2,
                        const float* __restrict__ W3, const float* __restrict__ b3,
                        float* __restrict__ out) {
    int g = blockIdx.x;
    int lane = threadIdx.x;
    __shared__ float t1[64];
    __shared__ float t2[32];
    const float* rp = rep + g * 128;
    float a = b1[lane];
#pragma unroll 8
    for (int i = 0; i < 128; i++) a = fmaf(rp[i], W1[i * 64 + lane], a);
    t1[lane] = gelu_f(a);
    __syncthreads();
    if (lane < 32) {
        float a2 = b2[lane];
#pragma unroll 8
        for (int i = 0; i < 64; i++) a2 = fmaf(t1[i], W2[i * 32 + lane], a2);
        t2[lane] = gelu_f(a2);
    }
    __syncthreads();
    if (lane < 32) {
        float p = t2[lane] * W3[lane];
#pragma unroll
        for (int o = 16; o > 0; o >>= 1) p += __shfl_xor(p, o, 64);
        if (lane == 0) out[g] = p + b3[0];
    }
}

extern "C" void kernel_launch(void* const* d_in, const int* in_sizes, int n_in,
                              void* d_out, int out_size, void* d_ws,
                              size_t ws_size, hipStream_t stream) {
    const float* x      = (const float*)d_in[0];
    const int*   eidx   = (const int*)d_in[1];
    const float* ea     = (const float*)d_in[2];
    const int*   batch  = (const int*)d_in[3];
    const float* in_W   = (const float*)d_in[4];
    const float* in_b   = (const float*)d_in[5];
    const float* in_lng = (const float*)d_in[6];
    const float* in_lnb = (const float*)d_in[7];
    const float* W_qkv  = (const float*)d_in[8];
    const float* b_qkv  = (const float*)d_in[9];
    const float* W_edge = (const float*)d_in[10];
    const float* W_skip = (const float*)d_in[11];
    const float* b_skip = (const float*)d_in[12];
    const float* W_beta = (const float*)d_in[13];
    const float* ln_g   = (const float*)d_in[14];
    const float* ln_b   = (const float*)d_in[15];
    const float* r1_W   = (const float*)d_in[16];
    const float* r1_b   = (const float*)d_in[17];
    const float* r2_W   = (const float*)d_in[18];
    const float* r2_b   = (const float*)d_in[19];
    const float* r3_W   = (const float*)d_in[20];
    const float* r3_b   = (const float*)d_in[21];

    int n = in_sizes[0] / 32;
    int E = in_sizes[2];
    const int* src = eidx;
    const int* dst = eidx + E;

    char* ws = (char*)d_ws;
    size_t off = 0;
    auto alloc = [&](size_t bytes) -> void* {
        void* p = ws + off;
        off = (off + bytes + 255) & ~(size_t)255;
        return p;
    };
    float* h    = (float*)alloc((size_t)n * 64 * 4);
    float* q    = (float*)alloc((size_t)n * 64 * 4);
    float* kv   = (float*)alloc((size_t)n * 128 * 4);
    float* oacc = (float*)alloc((size_t)n * 64 * 4);
    int* deg    = (int*)alloc((size_t)n * 4);
    int* excl   = (int*)alloc((size_t)n * 4);
    int* bsum   = (int*)alloc(512 * 4);
    int* row    = (int*)alloc((size_t)(n + 1) * 4);
    int* cursor = (int*)alloc((size_t)n * 4);
    int* esrc   = (int*)alloc((size_t)E * 4);
    float* eea  = (float*)alloc((size_t)E * 4);
    float* rep  = (float*)alloc(NGRAPH * 128 * 4);

    int nb4 = (n + 3) / 4;
    int nb16 = (n + 15) / 16;
    int nbs = (n + 255) / 256;
    int ebs = (E + 255) / 256;

    // CSR build (dst-sorted edge permutation, materialized src & edge_attr)
    hipMemsetAsync(deg, 0, (size_t)n * 4, stream);
    k_hist<<<ebs, 256, 0, stream>>>(dst, deg, E);
    k_scan1<<<nbs, 256, 0, stream>>>(deg, excl, bsum, n);
    k_scan2<<<1, 512, 0, stream>>>(bsum, nbs);
    k_scan3<<<nbs, 256, 0, stream>>>(excl, bsum, row, cursor, n, E);
    k_scatter<<<ebs, 256, 0, stream>>>(src, dst, ea, cursor, esrc, eea, E);

    k_input<<<nb4, 256, 0, stream>>>(x, in_W, in_b, in_lng, in_lnb, h, n);

    for (int l = 0; l < LAYERS; l++) {
        k_qkv<<<nb16, 256, 0, stream>>>(h, W_qkv + (size_t)l * 3 * 4096,
                                        b_qkv + (size_t)l * 192, q, kv, n);
        k_attn<<<nb4, 256, 0, stream>>>(q, kv, row, esrc, eea,
                                        W_edge + l * 64, oacc, n);
        k_node<<<nb16, 256, 0, stream>>>(h, oacc, W_skip + (size_t)l * 4096,
                                         b_skip + l * 64, W_beta + l * 192,
                                         ln_g + l * 64, ln_b + l * 64, n);
    }

    k_pool2<<<NGRAPH, 256, 0, stream>>>(h, batch, rep, n);
    k_final<<<NGRAPH, 64, 0, stream>>>(rep, r1_W, r1_b, r2_W, r2_b,
                                       r3_W, r3_b, (float*)d_out);
}

// Round 3
// 702.271 us; speedup vs baseline: 15.2801x; 1.3726x over previous
//
#include <hip/hip_runtime.h>
#include <math.h>
#include <float.h>

#define LAYERS 3
#define NGRAPH 128

__device__ __forceinline__ float gelu_f(float x) {
    return 0.5f * x * (1.0f + erff(x * 0.70710678118654752440f));
}

__device__ __forceinline__ float rl_f(float v, int i) {
    return __int_as_float(__builtin_amdgcn_readlane(__float_as_int(v), i));
}

// x + dpp_perm(x); masked rows add 0 (old=0, bound_ctrl=false)
template <int CTRL, int RMASK>
__device__ __forceinline__ float dpp_add(float x) {
    int t = __builtin_amdgcn_update_dpp(0, __float_as_int(x), CTRL, RMASK, 0xF, false);
    return x + __int_as_float(t);
}

// full 64-lane sum, VALU-only (no LDS/bpermute); returns wave-uniform scalar
__device__ __forceinline__ float wave_sum64(float v) {
    v = dpp_add<0xB1, 0xF>(v);   // quad_perm [1,0,3,2]  (xor 1)
    v = dpp_add<0x4E, 0xF>(v);   // quad_perm [2,3,0,1]  (xor 2)
    v = dpp_add<0x141, 0xF>(v);  // row_half_mirror      (xor 7)
    v = dpp_add<0x140, 0xF>(v);  // row_mirror           (xor 15)
    v = dpp_add<0x142, 0xA>(v);  // row_bcast15 -> rows 1,3
    v = dpp_add<0x143, 0xC>(v);  // row_bcast31 -> rows 2,3
    return rl_f(v, 63);
}

__device__ __forceinline__ int lbound(const int* __restrict__ a, int n, int key) {
    int lo = 0, hi = n;
    while (lo < hi) {
        int mid = (lo + hi) >> 1;
        if (a[mid] < key) lo = mid + 1; else hi = mid;
    }
    return lo;
}

// ---------------- CSR build ----------------
__global__ __launch_bounds__(256) void k_hist(const int* __restrict__ dst,
                                              int* __restrict__ deg, int E) {
    int e = blockIdx.x * 256 + threadIdx.x;
    if (e < E) atomicAdd(&deg[dst[e]], 1);
}

__global__ __launch_bounds__(256) void k_scan1(const int* __restrict__ deg,
                                               int* __restrict__ excl,
                                               int* __restrict__ bsum, int n) {
    __shared__ int s[256];
    int t = threadIdx.x;
    int i = blockIdx.x * 256 + t;
    int v = (i < n) ? deg[i] : 0;
    s[t] = v;
    __syncthreads();
    for (int off = 1; off < 256; off <<= 1) {
        int a = (t >= off) ? s[t - off] : 0;
        __syncthreads();
        s[t] += a;
        __syncthreads();
    }
    if (i < n) excl[i] = s[t] - v;
    if (t == 255) bsum[blockIdx.x] = s[255];
}

__global__ __launch_bounds__(512) void k_scan2(int* __restrict__ bsum, int nb) {
    __shared__ int s[512];
    int t = threadIdx.x;
    int v = (t < nb) ? bsum[t] : 0;
    s[t] = v;
    __syncthreads();
    for (int off = 1; off < 512; off <<= 1) {
        int a = (t >= off) ? s[t - off] : 0;
        __syncthreads();
        s[t] += a;
        __syncthreads();
    }
    if (t < nb) bsum[t] = s[t] - v;  // exclusive
}

__global__ __launch_bounds__(256) void k_scan3(const int* __restrict__ excl,
                                               const int* __restrict__ bsum,
                                               int* __restrict__ row,
                                               int* __restrict__ cursor,
                                               int n, int E) {
    int i = blockIdx.x * 256 + threadIdx.x;
    if (i < n) {
        int r = excl[i] + bsum[blockIdx.x];
        row[i] = r;
        cursor[i] = r;
    }
    if (blockIdx.x == 0 && threadIdx.x == 0) row[n] = E;
}

__global__ __launch_bounds__(256) void k_scatter(const int* __restrict__ src,
                                                 const int* __restrict__ dst,
                                                 const float* __restrict__ ea,
                                                 int* __restrict__ cursor,
                                                 int* __restrict__ esrc,
                                                 float* __restrict__ eea, int E) {
    int e = blockIdx.x * 256 + threadIdx.x;
    if (e >= E) return;
    int d = dst[e];
    int p = atomicAdd(&cursor[d], 1);
    esrc[p] = src[e];
    eea[p] = ea[e];
}

// ---------------- model ----------------
// h = LN(gelu(x @ in_W + in_b)); one wave per node; readlane broadcast
__global__ __launch_bounds__(256) void k_input(
    const float* __restrict__ x, const float* __restrict__ W,
    const float* __restrict__ b, const float* __restrict__ g,
    const float* __restrict__ be, float* __restrict__ h, int n) {
    int lane = threadIdx.x & 63;
    int node = blockIdx.x * 4 + (threadIdx.x >> 6);
    if (node >= n) return;
    float xv = x[(size_t)node * 32 + (lane & 31)];
    float acc = b[lane];
#pragma unroll 8
    for (int i = 0; i < 32; i++) acc = fmaf(rl_f(xv, i), W[i * 64 + lane], acc);
    acc = gelu_f(acc);
    float mu = wave_sum64(acc) * (1.0f / 64.0f);
    float d = acc - mu;
    float var = wave_sum64(d * d) * (1.0f / 64.0f);
    h[(size_t)node * 64 + lane] = d * rsqrtf(var + 1e-5f) * g[lane] + be[lane];
}

// q,k,v projections; 4 nodes per wave; readlane broadcast (no DS ops)
__global__ __launch_bounds__(256) void k_qkv(
    const float* __restrict__ h, const float* __restrict__ W,
    const float* __restrict__ bias, float* __restrict__ q,
    float* __restrict__ kvout, int n) {
    int lane = threadIdx.x & 63;
    int base = (blockIdx.x * 4 + (threadIdx.x >> 6)) * 4;
    if (base >= n) return;
    const float* Wq = W;
    const float* Wk = W + 4096;
    const float* Wv = W + 8192;
    float hreg[4];
#pragma unroll
    for (int t = 0; t < 4; t++)
        hreg[t] = h[(size_t)min(base + t, n - 1) * 64 + lane];
    float aq[4], ak[4], av[4];
#pragma unroll
    for (int t = 0; t < 4; t++) {
        aq[t] = bias[lane];
        ak[t] = bias[64 + lane];
        av[t] = bias[128 + lane];
    }
#pragma unroll 16
    for (int i = 0; i < 64; i++) {
        float wq = Wq[i * 64 + lane], wk = Wk[i * 64 + lane], wv = Wv[i * 64 + lane];
#pragma unroll
        for (int t = 0; t < 4; t++) {
            float hv = rl_f(hreg[t], i);
            aq[t] = fmaf(hv, wq, aq[t]);
            ak[t] = fmaf(hv, wk, ak[t]);
            av[t] = fmaf(hv, wv, av[t]);
        }
    }
#pragma unroll
    for (int t = 0; t < 4; t++) {
        int nd = base + t;
        if (nd < n) {
            q[(size_t)nd * 64 + lane] = aq[t];
            kvout[(size_t)nd * 128 + lane] = ak[t];
            kvout[(size_t)nd * 128 + 64 + lane] = av[t];
        }
    }
}

// attention: one wave per node, 4 edges in parallel per iteration.
// lane = g*16 + hh*4 + qd : g = edge slot, hh = head, qd = dim quad.
__global__ __launch_bounds__(256) void k_attn(
    const float* __restrict__ q, const float* __restrict__ kv,
    const int* __restrict__ row, const int* __restrict__ esrc,
    const float* __restrict__ eea, const float* __restrict__ We,
    float* __restrict__ out, int n) {
    int lane = threadIdx.x & 63;
    int node = blockIdx.x * 4 + (threadIdx.x >> 6);
    if (node >= n) return;
    int g = lane >> 4;
    int c16 = lane & 15;
    float4 qv = *(const float4*)(q + (size_t)node * 64 + c16 * 4);
    float4 wv = *(const float4*)(We + c16 * 4);
    int beg = row[node], end = row[node + 1];
    float m = -FLT_MAX, den = 0.f;
    float4 acc = {0.f, 0.f, 0.f, 0.f};
    for (int pos = beg; pos < end; pos += 4) {
        int idx = pos + g;
        bool valid = idx < end;
        int safe = valid ? idx : beg;  // beg<end guaranteed inside loop
        int s = esrc[safe];
        float a = eea[safe];
        const float4* kp = (const float4*)(kv + (size_t)s * 128);
        float4 kq = kp[c16];
        float4 vq = kp[16 + c16];
        float p = qv.x * fmaf(a, wv.x, kq.x) + qv.y * fmaf(a, wv.y, kq.y) +
                  qv.z * fmaf(a, wv.z, kq.z) + qv.w * fmaf(a, wv.w, kq.w);
        p = dpp_add<0xB1, 0xF>(p);  // quad xor1
        p = dpp_add<0x4E, 0xF>(p);  // quad xor2 -> 16-dim dot in all 4 lanes
        float alpha = valid ? p * 0.25f : -FLT_MAX;  // * 1/sqrt(16)
        float nm = fmaxf(m, alpha);
        float sc = __expf(m - nm);
        float ex = valid ? __expf(alpha - nm) : 0.f;
        den = fmaf(den, sc, ex);
        acc.x = fmaf(acc.x, sc, ex * fmaf(a, wv.x, vq.x));
        acc.y = fmaf(acc.y, sc, ex * fmaf(a, wv.y, vq.y));
        acc.z = fmaf(acc.z, sc, ex * fmaf(a, wv.z, vq.z));
        acc.w = fmaf(acc.w, sc, ex * fmaf(a, wv.w, vq.w));
        m = nm;
    }
    // merge the 4 edge-slot groups (xor 16, then xor 32)
#pragma unroll
    for (int mask = 16; mask <= 32; mask <<= 1) {
        float m2 = __shfl_xor(m, mask, 64);
        float d2 = __shfl_xor(den, mask, 64);
        float ax = __shfl_xor(acc.x, mask, 64);
        float ay = __shfl_xor(acc.y, mask, 64);
        float az = __shfl_xor(acc.z, mask, 64);
        float aw = __shfl_xor(acc.w, mask, 64);
        float nm = fmaxf(m, m2);
        float s1 = __expf(m - nm), s2 = __expf(m2 - nm);
        den = den * s1 + d2 * s2;
        acc.x = acc.x * s1 + ax * s2;
        acc.y = acc.y * s1 + ay * s2;
        acc.z = acc.z * s1 + az * s2;
        acc.w = acc.w * s1 + aw * s2;
        m = nm;
    }
    if (g == 0) {
        float inv = 1.0f / (den + 1e-16f);
        float4 o = {acc.x * inv, acc.y * inv, acc.z * inv, acc.w * inv};
        *(float4*)(out + (size_t)node * 64 + c16 * 4) = o;
    }
}

// per node: x_r = h@W_skip+b; beta gate; h = LN(gelu(out2)+res); 4 nodes/wave
__global__ __launch_bounds__(256) void k_node(
    float* __restrict__ h, const float* __restrict__ o_in,
    const float* __restrict__ Ws, const float* __restrict__ bs,
    const float* __restrict__ Wb, const float* __restrict__ lg,
    const float* __restrict__ lb, int n) {
    int lane = threadIdx.x & 63;
    int base = (blockIdx.x * 4 + (threadIdx.x >> 6)) * 4;
    if (base >= n) return;
    float hreg[4], xr[4];
#pragma unroll
    for (int t = 0; t < 4; t++) {
        hreg[t] = h[(size_t)min(base + t, n - 1) * 64 + lane];
        xr[t] = bs[lane];
    }
#pragma unroll 16
    for (int i = 0; i < 64; i++) {
        float w = Ws[i * 64 + lane];
#pragma unroll
        for (int t = 0; t < 4; t++) xr[t] = fmaf(rl_f(hreg[t], i), w, xr[t]);
    }
    float wb0 = Wb[lane], wb1 = Wb[64 + lane], wb2 = Wb[128 + lane];
    float lgv = lg[lane], lbv = lb[lane];
#pragma unroll
    for (int t = 0; t < 4; t++) {
        int nd = base + t;
        if (nd >= n) break;
        float o = o_in[(size_t)nd * 64 + lane];
        float cb = o * wb0 + xr[t] * wb1 + (o - xr[t]) * wb2;
        cb = wave_sum64(cb);
        float beta = 1.0f / (1.0f + expf(-cb));
        float o2 = fmaf(beta, xr[t] - o, o);
        float gv = gelu_f(o2) + hreg[t];
        float mu = wave_sum64(gv) * (1.0f / 64.0f);
        float dd = gv - mu;
        float var = wave_sum64(dd * dd) * (1.0f / 64.0f);
        h[(size_t)nd * 64 + lane] = dd * rsqrtf(var + 1e-5f) * lgv + lbv;
    }
}

// pooling: one block per graph over sorted batch; no atomics
__global__ __launch_bounds__(256) void k_pool2(const float* __restrict__ h,
                                               const int* __restrict__ batch,
                                               float* __restrict__ rep, int n) {
    int g = blockIdx.x;
    int lane = threadIdx.x & 63, wid = threadIdx.x >> 6;
    int start = lbound(batch, n, g), end = lbound(batch, n, g + 1);
    float s = 0.f, mx = -FLT_MAX;
    for (int i = start + wid; i < end; i += 4) {
        float v = h[(size_t)i * 64 + lane];
        s += v;
        mx = fmaxf(mx, v);
    }
    __shared__ float ssum[4][64], smax[4][64];
    ssum[wid][lane] = s;
    smax[wid][lane] = mx;
    __syncthreads();
    if (wid == 0) {
#pragma unroll
        for (int w = 1; w < 4; w++) {
            s += ssum[w][lane];
            mx = fmaxf(mx, smax[w][lane]);
        }
        float c = fmaxf((float)(end - start), 1.0f);
        rep[g * 128 + lane] = s / c;
        rep[g * 128 + 64 + lane] = mx;
    }
}

// final MLP head: one block (64 threads) per graph
__global__ void k_final(const float* __restrict__ rep,
                        const float* __restrict__ W1, const float* __restrict__ b1,
                        const float* __restrict__ W2, const float* __restrict__ b2,
                        const float* __restrict__ W3, const float* __restrict__ b3,
                        float* __restrict__ out) {
    int g = blockIdx.x;
    int lane = threadIdx.x;
    __shared__ float t1[64];
    __shared__ float t2[32];
    const float* rp = rep + g * 128;
    float a = b1[lane];
#pragma unroll 8
    for (int i = 0; i < 128; i++) a = fmaf(rp[i], W1[i * 64 + lane], a);
    t1[lane] = gelu_f(a);
    __syncthreads();
    if (lane < 32) {
        float a2 = b2[lane];
#pragma unroll 8
        for (int i = 0; i < 64; i++) a2 = fmaf(t1[i], W2[i * 32 + lane], a2);
        t2[lane] = gelu_f(a2);
    }
    __syncthreads();
    if (lane < 32) {
        float p = t2[lane] * W3[lane];
#pragma unroll
        for (int o = 16; o > 0; o >>= 1) p += __shfl_xor(p, o, 64);
        if (lane == 0) out[g] = p + b3[0];
    }
}

extern "C" void kernel_launch(void* const* d_in, const int* in_sizes, int n_in,
                              void* d_out, int out_size, void* d_ws,
                              size_t ws_size, hipStream_t stream) {
    const float* x      = (const float*)d_in[0];
    const int*   eidx   = (const int*)d_in[1];
    const float* ea     = (const float*)d_in[2];
    const int*   batch  = (const int*)d_in[3];
    const float* in_W   = (const float*)d_in[4];
    const float* in_b   = (const float*)d_in[5];
    const float* in_lng = (const float*)d_in[6];
    const float* in_lnb = (const float*)d_in[7];
    const float* W_qkv  = (const float*)d_in[8];
    const float* b_qkv  = (const float*)d_in[9];
    const float* W_edge = (const float*)d_in[10];
    const float* W_skip = (const float*)d_in[11];
    const float* b_skip = (const float*)d_in[12];
    const float* W_beta = (const float*)d_in[13];
    const float* ln_g   = (const float*)d_in[14];
    const float* ln_b   = (const float*)d_in[15];
    const float* r1_W   = (const float*)d_in[16];
    const float* r1_b   = (const float*)d_in[17];
    const float* r2_W   = (const float*)d_in[18];
    const float* r2_b   = (const float*)d_in[19];
    const float* r3_W   = (const float*)d_in[20];
    const float* r3_b   = (const float*)d_in[21];

    int n = in_sizes[0] / 32;
    int E = in_sizes[2];
    const int* src = eidx;
    const int* dst = eidx + E;

    char* ws = (char*)d_ws;
    size_t off = 0;
    auto alloc = [&](size_t bytes) -> void* {
        void* p = ws + off;
        off = (off + bytes + 255) & ~(size_t)255;
        return p;
    };
    float* h    = (float*)alloc((size_t)n * 64 * 4);
    float* q    = (float*)alloc((size_t)n * 64 * 4);
    float* kv   = (float*)alloc((size_t)n * 128 * 4);
    float* oacc = (float*)alloc((size_t)n * 64 * 4);
    int* deg    = (int*)alloc((size_t)n * 4);
    int* excl   = (int*)alloc((size_t)n * 4);
    int* bsum   = (int*)alloc(512 * 4);
    int* row    = (int*)alloc((size_t)(n + 1) * 4);
    int* cursor = (int*)alloc((size_t)n * 4);
    int* esrc   = (int*)alloc((size_t)E * 4);
    float* eea  = (float*)alloc((size_t)E * 4);
    float* rep  = (float*)alloc(NGRAPH * 128 * 4);

    int nb4 = (n + 3) / 4;
    int nb16 = (n + 15) / 16;
    int nbs = (n + 255) / 256;
    int ebs = (E + 255) / 256;

    // CSR build (dst-sorted edge permutation, materialized src & edge_attr)
    hipMemsetAsync(deg, 0, (size_t)n * 4, stream);
    k_hist<<<ebs, 256, 0, stream>>>(dst, deg, E);
    k_scan1<<<nbs, 256, 0, stream>>>(deg, excl, bsum, n);
    k_scan2<<<1, 512, 0, stream>>>(bsum, nbs);
    k_scan3<<<nbs, 256, 0, stream>>>(excl, bsum, row, cursor, n, E);
    k_scatter<<<ebs, 256, 0, stream>>>(src, dst, ea, cursor, esrc, eea, E);

    k_input<<<nb4, 256, 0, stream>>>(x, in_W, in_b, in_lng, in_lnb, h, n);

    for (int l = 0; l < LAYERS; l++) {
        k_qkv<<<nb16, 256, 0, stream>>>(h, W_qkv + (size_t)l * 3 * 4096,
                                        b_qkv + (size_t)l * 192, q, kv, n);
        k_attn<<<nb4, 256, 0, stream>>>(q, kv, row, esrc, eea,
                                        W_edge + l * 64, oacc, n);
        k_node<<<nb16, 256, 0, stream>>>(h, oacc, W_skip + (size_t)l * 4096,
                                         b_skip + l * 64, W_beta + l * 192,
                                         ln_g + l * 64, ln_b + l * 64, n);
    }

    k_pool2<<<NGRAPH, 256, 0, stream>>>(h, batch, rep, n);
    k_final<<<NGRAPH, 64, 0, stream>>>(rep, r1_W, r1_b, r2_W, r2_b,
                                       r3_W, r3_b, (float*)d_out);
}

// Round 4
// 645.351 us; speedup vs baseline: 16.6278x; 1.0882x over previous
//
#include <hip/hip_runtime.h>
#include <math.h>
#include <float.h>

#define LAYERS 3
#define NGRAPH 128

__device__ __forceinline__ float gelu_f(float x) {
    return 0.5f * x * (1.0f + erff(x * 0.70710678118654752440f));
}

__device__ __forceinline__ float rl_f(float v, int i) {
    return __int_as_float(__builtin_amdgcn_readlane(__float_as_int(v), i));
}

// x + dpp_perm(x); masked rows add 0 (old=0, bound_ctrl=false)
template <int CTRL, int RMASK>
__device__ __forceinline__ float dpp_add(float x) {
    int t = __builtin_amdgcn_update_dpp(0, __float_as_int(x), CTRL, RMASK, 0xF, false);
    return x + __int_as_float(t);
}

// full 64-lane sum, VALU-only; returns wave-uniform scalar
__device__ __forceinline__ float wave_sum64(float v) {
    v = dpp_add<0xB1, 0xF>(v);   // quad_perm xor1
    v = dpp_add<0x4E, 0xF>(v);   // quad_perm xor2
    v = dpp_add<0x141, 0xF>(v);  // row_half_mirror
    v = dpp_add<0x140, 0xF>(v);  // row_mirror
    v = dpp_add<0x142, 0xA>(v);  // row_bcast15
    v = dpp_add<0x143, 0xC>(v);  // row_bcast31
    return rl_f(v, 63);
}

__device__ __forceinline__ unsigned int f2mono(float f) {
    unsigned int u = __float_as_uint(f);
    return (u & 0x80000000u) ? ~u : (u | 0x80000000u);
}
__device__ __forceinline__ float mono2f(unsigned int u) {
    return (u & 0x80000000u) ? __uint_as_float(u ^ 0x80000000u)
                             : __uint_as_float(~u);
}

// ---------------- CSR build ----------------
__global__ __launch_bounds__(256) void k_hist(const int* __restrict__ dst,
                                              int* __restrict__ deg, int E) {
    int e = blockIdx.x * 256 + threadIdx.x;
    if (e < E) atomicAdd(&deg[dst[e]], 1);
}

__global__ __launch_bounds__(256) void k_scan1(const int* __restrict__ deg,
                                               int* __restrict__ excl,
                                               int* __restrict__ bsum, int n) {
    __shared__ int s[256];
    int t = threadIdx.x;
    int i = blockIdx.x * 256 + t;
    int v = (i < n) ? deg[i] : 0;
    s[t] = v;
    __syncthreads();
    for (int off = 1; off < 256; off <<= 1) {
        int a = (t >= off) ? s[t - off] : 0;
        __syncthreads();
        s[t] += a;
        __syncthreads();
    }
    if (i < n) excl[i] = s[t] - v;
    if (t == 255) bsum[blockIdx.x] = s[255];
}

__global__ __launch_bounds__(512) void k_scan2(int* __restrict__ bsum, int nb) {
    __shared__ int s[512];
    int t = threadIdx.x;
    int v = (t < nb) ? bsum[t] : 0;
    s[t] = v;
    __syncthreads();
    for (int off = 1; off < 512; off <<= 1) {
        int a = (t >= off) ? s[t - off] : 0;
        __syncthreads();
        s[t] += a;
        __syncthreads();
    }
    if (t < nb) bsum[t] = s[t] - v;  // exclusive
}

__global__ __launch_bounds__(256) void k_scan3(const int* __restrict__ excl,
                                               const int* __restrict__ bsum,
                                               int* __restrict__ row,
                                               int* __restrict__ cursor,
                                               int n, int E) {
    int i = blockIdx.x * 256 + threadIdx.x;
    if (i < n) {
        int r = excl[i] + bsum[blockIdx.x];
        row[i] = r;
        cursor[i] = r;
    }
    if (blockIdx.x == 0 && threadIdx.x == 0) row[n] = E;
}

__global__ __launch_bounds__(256) void k_scatter(const int* __restrict__ src,
                                                 const int* __restrict__ dst,
                                                 const float* __restrict__ ea,
                                                 int* __restrict__ cursor,
                                                 int2* __restrict__ ep, int E) {
    int e = blockIdx.x * 256 + threadIdx.x;
    if (e >= E) return;
    int d = dst[e];
    int p = atomicAdd(&cursor[d], 1);
    ep[p] = make_int2(src[e], __float_as_int(ea[e]));
}

// ---------------- model ----------------
// fused: h = LN(gelu(x@in_W+in_b)); then layer-0 q,k,v. 4 nodes per wave.
__global__ __launch_bounds__(256) void k_in_qkv(
    const float* __restrict__ x, const float* __restrict__ W,
    const float* __restrict__ b, const float* __restrict__ g,
    const float* __restrict__ be, const float* __restrict__ Wn,
    const float* __restrict__ bn, float* __restrict__ h,
    float* __restrict__ q, float* __restrict__ kvout, int n) {
    int lane = threadIdx.x & 63;
    int base = (blockIdx.x * 4 + (threadIdx.x >> 6)) * 4;
    if (base >= n) return;
    float xv[4], hreg[4];
#pragma unroll
    for (int t = 0; t < 4; t++)
        xv[t] = x[(size_t)min(base + t, n - 1) * 32 + (lane & 31)];
    float bl = b[lane], gl = g[lane], bel = be[lane];
#pragma unroll
    for (int t = 0; t < 4; t++) hreg[t] = bl;
#pragma unroll 8
    for (int i = 0; i < 32; i++) {
        float w = W[i * 64 + lane];
#pragma unroll
        for (int t = 0; t < 4; t++) hreg[t] = fmaf(rl_f(xv[t], i), w, hreg[t]);
    }
#pragma unroll
    for (int t = 0; t < 4; t++) {
        float acc = gelu_f(hreg[t]);
        float mu = wave_sum64(acc) * (1.0f / 64.0f);
        float d = acc - mu;
        float var = wave_sum64(d * d) * (1.0f / 64.0f);
        hreg[t] = d * rsqrtf(var + 1e-5f) * gl + bel;
        int nd = base + t;
        if (nd < n) h[(size_t)nd * 64 + lane] = hreg[t];
    }
    // layer-0 qkv
    const float* Wq = Wn;
    const float* Wk = Wn + 4096;
    const float* Wv = Wn + 8192;
    float aq[4], ak[4], av[4];
#pragma unroll
    for (int t = 0; t < 4; t++) {
        aq[t] = bn[lane];
        ak[t] = bn[64 + lane];
        av[t] = bn[128 + lane];
    }
#pragma unroll 16
    for (int i = 0; i < 64; i++) {
        float wq = Wq[i * 64 + lane], wk = Wk[i * 64 + lane], wv = Wv[i * 64 + lane];
#pragma unroll
        for (int t = 0; t < 4; t++) {
            float hv = rl_f(hreg[t], i);
            aq[t] = fmaf(hv, wq, aq[t]);
            ak[t] = fmaf(hv, wk, ak[t]);
            av[t] = fmaf(hv, wv, av[t]);
        }
    }
#pragma unroll
    for (int t = 0; t < 4; t++) {
        int nd = base + t;
        if (nd < n) {
            q[(size_t)nd * 64 + lane] = aq[t];
            kvout[(size_t)nd * 128 + lane] = ak[t];
            kvout[(size_t)nd * 128 + 64 + lane] = av[t];
        }
    }
}

// attention: one wave per node, 4 edges in parallel per iteration.
__global__ __launch_bounds__(256) void k_attn(
    const float* __restrict__ q, const float* __restrict__ kv,
    const int* __restrict__ row, const int2* __restrict__ ep,
    const float* __restrict__ We, float* __restrict__ out, int n) {
    int lane = threadIdx.x & 63;
    int node = blockIdx.x * 4 + (threadIdx.x >> 6);
    if (node >= n) return;
    int g = lane >> 4;
    int c16 = lane & 15;
    float4 qv = *(const float4*)(q + (size_t)node * 64 + c16 * 4);
    float4 wv = *(const float4*)(We + c16 * 4);
    int beg = row[node], end = row[node + 1];
    float m = -FLT_MAX, den = 0.f;
    float4 acc = {0.f, 0.f, 0.f, 0.f};
    for (int pos = beg; pos < end; pos += 4) {
        int idx = pos + g;
        bool valid = idx < end;
        int safe = valid ? idx : beg;
        int2 pr = ep[safe];
        int s = pr.x;
        float a = __int_as_float(pr.y);
        const float4* kp = (const float4*)(kv + (size_t)s * 128);
        float4 kq = kp[c16];
        float4 vq = kp[16 + c16];
        float p = qv.x * fmaf(a, wv.x, kq.x) + qv.y * fmaf(a, wv.y, kq.y) +
                  qv.z * fmaf(a, wv.z, kq.z) + qv.w * fmaf(a, wv.w, kq.w);
        p = dpp_add<0xB1, 0xF>(p);
        p = dpp_add<0x4E, 0xF>(p);
        float alpha = valid ? p * 0.25f : -FLT_MAX;
        float nm = fmaxf(m, alpha);
        float sc = __expf(m - nm);
        float ex = valid ? __expf(alpha - nm) : 0.f;
        den = fmaf(den, sc, ex);
        acc.x = fmaf(acc.x, sc, ex * fmaf(a, wv.x, vq.x));
        acc.y = fmaf(acc.y, sc, ex * fmaf(a, wv.y, vq.y));
        acc.z = fmaf(acc.z, sc, ex * fmaf(a, wv.z, vq.z));
        acc.w = fmaf(acc.w, sc, ex * fmaf(a, wv.w, vq.w));
        m = nm;
    }
#pragma unroll
    for (int mask = 16; mask <= 32; mask <<= 1) {
        float m2 = __shfl_xor(m, mask, 64);
        float d2 = __shfl_xor(den, mask, 64);
        float ax = __shfl_xor(acc.x, mask, 64);
        float ay = __shfl_xor(acc.y, mask, 64);
        float az = __shfl_xor(acc.z, mask, 64);
        float aw = __shfl_xor(acc.w, mask, 64);
        float nm = fmaxf(m, m2);
        float s1 = __expf(m - nm), s2 = __expf(m2 - nm);
        den = den * s1 + d2 * s2;
        acc.x = acc.x * s1 + ax * s2;
        acc.y = acc.y * s1 + ay * s2;
        acc.z = acc.z * s1 + az * s2;
        acc.w = acc.w * s1 + aw * s2;
        m = nm;
    }
    if (g == 0) {
        float inv = 1.0f / (den + 1e-16f);
        float4 o = {acc.x * inv, acc.y * inv, acc.z * inv, acc.w * inv};
        *(float4*)(out + (size_t)node * 64 + c16 * 4) = o;
    }
}

// fused: node update (skip+beta gate+LN) then next layer qkv. 4 nodes/wave.
template <int DO_QKV>
__global__ __launch_bounds__(256) void k_node_qkv(
    float* __restrict__ h, const float* __restrict__ o_in,
    const float* __restrict__ Ws, const float* __restrict__ bs,
    const float* __restrict__ Wb, const float* __restrict__ lg,
    const float* __restrict__ lb, const float* __restrict__ Wn,
    const float* __restrict__ bn, float* __restrict__ q,
    float* __restrict__ kvout, int n) {
    int lane = threadIdx.x & 63;
    int base = (blockIdx.x * 4 + (threadIdx.x >> 6)) * 4;
    if (base >= n) return;
    float hreg[4], xr[4];
#pragma unroll
    for (int t = 0; t < 4; t++) {
        hreg[t] = h[(size_t)min(base + t, n - 1) * 64 + lane];
        xr[t] = bs[lane];
    }
#pragma unroll 16
    for (int i = 0; i < 64; i++) {
        float w = Ws[i * 64 + lane];
#pragma unroll
        for (int t = 0; t < 4; t++) xr[t] = fmaf(rl_f(hreg[t], i), w, xr[t]);
    }
    float wb0 = Wb[lane], wb1 = Wb[64 + lane], wb2 = Wb[128 + lane];
    float lgv = lg[lane], lbv = lb[lane];
#pragma unroll
    for (int t = 0; t < 4; t++) {
        int nd = base + t;
        if (nd >= n) continue;
        float o = o_in[(size_t)nd * 64 + lane];
        float cb = o * wb0 + xr[t] * wb1 + (o - xr[t]) * wb2;
        cb = wave_sum64(cb);
        float beta = 1.0f / (1.0f + expf(-cb));
        float o2 = fmaf(beta, xr[t] - o, o);
        float gv = gelu_f(o2) + hreg[t];
        float mu = wave_sum64(gv) * (1.0f / 64.0f);
        float dd = gv - mu;
        float var = wave_sum64(dd * dd) * (1.0f / 64.0f);
        float hn = dd * rsqrtf(var + 1e-5f) * lgv + lbv;
        hreg[t] = hn;
        h[(size_t)nd * 64 + lane] = hn;
    }
    if (DO_QKV) {
        const float* Wq = Wn;
        const float* Wk = Wn + 4096;
        const float* Wv = Wn + 8192;
        float aq[4], ak[4], av[4];
#pragma unroll
        for (int t = 0; t < 4; t++) {
            aq[t] = bn[lane];
            ak[t] = bn[64 + lane];
            av[t] = bn[128 + lane];
        }
#pragma unroll 16
        for (int i = 0; i < 64; i++) {
            float wq = Wq[i * 64 + lane], wk = Wk[i * 64 + lane],
                  wvv = Wv[i * 64 + lane];
#pragma unroll
            for (int t = 0; t < 4; t++) {
                float hv = rl_f(hreg[t], i);
                aq[t] = fmaf(hv, wq, aq[t]);
                ak[t] = fmaf(hv, wk, ak[t]);
                av[t] = fmaf(hv, wvv, av[t]);
            }
        }
#pragma unroll
        for (int t = 0; t < 4; t++) {
            int nd = base + t;
            if (nd < n) {
                q[(size_t)nd * 64 + lane] = aq[t];
                kvout[(size_t)nd * 128 + lane] = ak[t];
                kvout[(size_t)nd * 128 + 64 + lane] = av[t];
            }
        }
    }
}

// pooling phase 1: each wave owns a contiguous node chunk (batch sorted);
// register-accumulate per graph-run, flush once per run via atomics.
__global__ __launch_bounds__(256) void k_pool3(
    const float* __restrict__ h, const int* __restrict__ batch,
    float* __restrict__ gsum, unsigned int* __restrict__ gmax,
    float* __restrict__ cnt, int n, int chunk) {
    int wave = (blockIdx.x * 256 + threadIdx.x) >> 6;
    int lane = threadIdx.x & 63;
    int i0 = wave * chunk;
    if (i0 >= n) return;
    int i1 = min(n, i0 + chunk);
    int cur = batch[i0];
    float s = 0.f, mx = -FLT_MAX;
    int run = 0;
    for (int i = i0; i < i1; ++i) {
        int g = batch[i];
        if (g != cur) {
            atomicAdd(gsum + cur * 64 + lane, s);
            atomicMax(gmax + cur * 64 + lane, f2mono(mx));
            if (lane == 0) atomicAdd(cnt + cur, (float)run);
            s = 0.f;
            mx = -FLT_MAX;
            run = 0;
            cur = g;
        }
        float v = h[(size_t)i * 64 + lane];
        s += v;
        mx = fmaxf(mx, v);
        ++run;
    }
    atomicAdd(gsum + cur * 64 + lane, s);
    atomicMax(gmax + cur * 64 + lane, f2mono(mx));
    if (lane == 0) atomicAdd(cnt + cur, (float)run);
}

// final MLP head: one block (64 threads) per graph
__global__ void k_final(const float* __restrict__ gsum,
                        const unsigned int* __restrict__ gmax,
                        const float* __restrict__ cnt,
                        const float* __restrict__ W1, const float* __restrict__ b1,
                        const float* __restrict__ W2, const float* __restrict__ b2,
                        const float* __restrict__ W3, const float* __restrict__ b3,
                        float* __restrict__ out) {
    int g = blockIdx.x;
    int lane = threadIdx.x;
    __shared__ float rep[128];
    __shared__ float t1[64];
    __shared__ float t2[32];
    float c = fmaxf(cnt[g], 1.0f);
    rep[lane] = gsum[g * 64 + lane] / c;
    rep[64 + lane] = mono2f(gmax[g * 64 + lane]);
    __syncthreads();
    float a = b1[lane];
#pragma unroll 8
    for (int i = 0; i < 128; i++) a = fmaf(rep[i], W1[i * 64 + lane], a);
    t1[lane] = gelu_f(a);
    __syncthreads();
    if (lane < 32) {
        float a2 = b2[lane];
#pragma unroll 8
        for (int i = 0; i < 64; i++) a2 = fmaf(t1[i], W2[i * 32 + lane], a2);
        t2[lane] = gelu_f(a2);
    }
    __syncthreads();
    if (lane < 32) {
        float p = t2[lane] * W3[lane];
#pragma unroll
        for (int o = 16; o > 0; o >>= 1) p += __shfl_xor(p, o, 64);
        if (lane == 0) out[g] = p + b3[0];
    }
}

extern "C" void kernel_launch(void* const* d_in, const int* in_sizes, int n_in,
                              void* d_out, int out_size, void* d_ws,
                              size_t ws_size, hipStream_t stream) {
    const float* x      = (const float*)d_in[0];
    const int*   eidx   = (const int*)d_in[1];
    const float* ea     = (const float*)d_in[2];
    const int*   batch  = (const int*)d_in[3];
    const float* in_W   = (const float*)d_in[4];
    const float* in_b   = (const float*)d_in[5];
    const float* in_lng = (const float*)d_in[6];
    const float* in_lnb = (const float*)d_in[7];
    const float* W_qkv  = (const float*)d_in[8];
    const float* b_qkv  = (const float*)d_in[9];
    const float* W_edge = (const float*)d_in[10];
    const float* W_skip = (const float*)d_in[11];
    const float* b_skip = (const float*)d_in[12];
    const float* W_beta = (const float*)d_in[13];
    const float* ln_g   = (const float*)d_in[14];
    const float* ln_b   = (const float*)d_in[15];
    const float* r1_W   = (const float*)d_in[16];
    const float* r1_b   = (const float*)d_in[17];
    const float* r2_W   = (const float*)d_in[18];
    const float* r2_b   = (const float*)d_in[19];
    const float* r3_W   = (const float*)d_in[20];
    const float* r3_b   = (const float*)d_in[21];

    int n = in_sizes[0] / 32;
    int E = in_sizes[2];
    const int* src = eidx;
    const int* dst = eidx + E;

    char* ws = (char*)d_ws;
    size_t off = 0;
    auto alloc = [&](size_t bytes) -> void* {
        void* p = ws + off;
        off = (off + bytes + 255) & ~(size_t)255;
        return p;
    };
    float* h    = (float*)alloc((size_t)n * 64 * 4);
    float* q    = (float*)alloc((size_t)n * 64 * 4);
    float* kv   = (float*)alloc((size_t)n * 128 * 4);
    float* oacc = (float*)alloc((size_t)n * 64 * 4);
    int* deg    = (int*)alloc((size_t)n * 4);
    int* excl   = (int*)alloc((size_t)n * 4);
    int* bsum   = (int*)alloc(512 * 4);
    int* row    = (int*)alloc((size_t)(n + 1) * 4);
    int* cursor = (int*)alloc((size_t)n * 4);
    int2* ep    = (int2*)alloc((size_t)E * 8);
    // pool buffers contiguous -> single memset
    float* gsum = (float*)alloc((NGRAPH * 64 * 2 + NGRAPH) * 4);
    unsigned int* gmax = (unsigned int*)(gsum + NGRAPH * 64);
    float* cnt  = gsum + NGRAPH * 128;

    int nb4 = (n + 3) / 4;
    int nb16 = (n + 15) / 16;
    int nbs = (n + 255) / 256;
    int ebs = (E + 255) / 256;

    // CSR build
    hipMemsetAsync(deg, 0, (size_t)n * 4, stream);
    k_hist<<<ebs, 256, 0, stream>>>(dst, deg, E);
    k_scan1<<<nbs, 256, 0, stream>>>(deg, excl, bsum, n);
    k_scan2<<<1, 512, 0, stream>>>(bsum, nbs);
    k_scan3<<<nbs, 256, 0, stream>>>(excl, bsum, row, cursor, n, E);
    k_scatter<<<ebs, 256, 0, stream>>>(src, dst, ea, cursor, ep, E);

    k_in_qkv<<<nb16, 256, 0, stream>>>(x, in_W, in_b, in_lng, in_lnb,
                                       W_qkv, b_qkv, h, q, kv, n);

    for (int l = 0; l < LAYERS; l++) {
        k_attn<<<nb4, 256, 0, stream>>>(q, kv, row, ep, W_edge + l * 64, oacc, n);
        if (l + 1 < LAYERS) {
            k_node_qkv<1><<<nb16, 256, 0, stream>>>(
                h, oacc, W_skip + (size_t)l * 4096, b_skip + l * 64,
                W_beta + l * 192, ln_g + l * 64, ln_b + l * 64,
                W_qkv + (size_t)(l + 1) * 3 * 4096, b_qkv + (size_t)(l + 1) * 192,
                q, kv, n);
        } else {
            k_node_qkv<0><<<nb16, 256, 0, stream>>>(
                h, oacc, W_skip + (size_t)l * 4096, b_skip + l * 64,
                W_beta + l * 192, ln_g + l * 64, ln_b + l * 64,
                nullptr, nullptr, nullptr, nullptr, n);
        }
    }

    hipMemsetAsync(gsum, 0, (NGRAPH * 64 * 2 + NGRAPH) * 4, stream);
    int nwaves = 4096;
    int chunk = (n + nwaves - 1) / nwaves;
    k_pool3<<<nwaves / 4, 256, 0, stream>>>(h, batch, gsum, gmax, cnt, n, chunk);
    k_final<<<NGRAPH, 64, 0, stream>>>(gsum, gmax, cnt, r1_W, r1_b, r2_W, r2_b,
                                       r3_W, r3_b, (float*)d_out);
}

// Round 5
// 446.466 us; speedup vs baseline: 24.0350x; 1.4455x over previous
//
#include <hip/hip_runtime.h>
#include <math.h>
#include <float.h>

#define LAYERS 3
#define NGRAPH 128

typedef __attribute__((ext_vector_type(8))) short bf16x8;
typedef __attribute__((ext_vector_type(4))) float f32x4;

union bfr { int4 i; bf16x8 b; };

__device__ __forceinline__ float gelu_f(float x) {
    return 0.5f * x * (1.0f + erff(x * 0.70710678118654752440f));
}

// x + dpp_perm(x); masked rows add 0 (old=0, bound_ctrl=false)
template <int CTRL, int RMASK>
__device__ __forceinline__ float dpp_add(float x) {
    int t = __builtin_amdgcn_update_dpp(0, __float_as_int(x), CTRL, RMASK, 0xF, false);
    return x + __int_as_float(t);
}

// sum over each 16-lane group (row); result in all 16 lanes
__device__ __forceinline__ float sum16(float v) {
    v = dpp_add<0xB1, 0xF>(v);   // quad_perm xor1
    v = dpp_add<0x4E, 0xF>(v);   // quad_perm xor2
    v = dpp_add<0x141, 0xF>(v);  // row_half_mirror (xor across quads in half)
    v = dpp_add<0x140, 0xF>(v);  // row_mirror (xor across halves of row)
    return v;
}

__device__ __forceinline__ unsigned int f2mono(float f) {
    unsigned int u = __float_as_uint(f);
    return (u & 0x80000000u) ? ~u : (u | 0x80000000u);
}
__device__ __forceinline__ float mono2f(unsigned int u) {
    return (u & 0x80000000u) ? __uint_as_float(u ^ 0x80000000u)
                             : __uint_as_float(~u);
}

// split-bf16 fragment build: hi = trunc-bf16(x), lo = trunc-bf16(x - hi)
__device__ __forceinline__ void cvt_frag(const float4& f0, const float4& f1,
                                         bf16x8& hi, bf16x8& lo) {
    float ff[8] = {f0.x, f0.y, f0.z, f0.w, f1.x, f1.y, f1.z, f1.w};
#pragma unroll
    for (int j = 0; j < 8; j++) {
        unsigned u = __float_as_uint(ff[j]);
        hi[j] = (short)(u >> 16);
        float hf = __uint_as_float(u & 0xFFFF0000u);
        lo[j] = (short)(__float_as_uint(ff[j] - hf) >> 16);
    }
}

// acc += A * B_tile with 3-term split (drops lo*lo, ~2^-16 relative)
__device__ __forceinline__ f32x4 mm3(const bf16x8& ahi, const bf16x8& alo,
                                     const int4* __restrict__ pk, int tile,
                                     int lane, f32x4 acc) {
    bfr bh, bl;
    bh.i = pk[tile * 128 + lane];
    bl.i = pk[tile * 128 + 64 + lane];
    acc = __builtin_amdgcn_mfma_f32_16x16x32_bf16(alo, bh.b, acc, 0, 0, 0);
    acc = __builtin_amdgcn_mfma_f32_16x16x32_bf16(ahi, bl.b, acc, 0, 0, 0);
    acc = __builtin_amdgcn_mfma_f32_16x16x32_bf16(ahi, bh.b, acc, 0, 0, 0);
    return acc;
}

// ---------------- weight packing (once per launch) ----------------
// B-fragment: lane holds W[kt*32 + (lane>>4)*8 + j][jt*16 + (lane&15)], j=0..7
// tile t = jt*KT + kt; per tile: hi int4 at t*128+lane, lo at t*128+64+lane
__global__ __launch_bounds__(256) void k_cvt(
    const float* __restrict__ in_W, const float* __restrict__ W_skip,
    const float* __restrict__ W_qkv, int4* __restrict__ pk_in,
    int4* __restrict__ pk_skip, int4* __restrict__ pk_qkv) {
    int w = (blockIdx.x * 256 + threadIdx.x) >> 6;
    if (w >= 100) return;
    int lane = threadIdx.x & 63;
    const float* src;
    int4* dst;
    int kt, jt, qkvmode = 0;
    if (w < 4) {
        kt = 0; jt = w;
        src = in_W;
        dst = pk_in + w * 128;
    } else {
        int l = (w - 4) >> 5, r = (w - 4) & 31;
        if (r < 8) {
            kt = r & 1; jt = r >> 1;
            src = W_skip + l * 4096;
            dst = pk_skip + (l * 8 + r) * 128;
        } else {
            int tq = r - 8;
            kt = tq & 1; jt = tq >> 1;
            src = W_qkv + l * 12288;
            dst = pk_qkv + (l * 24 + tq) * 128;
            qkvmode = 1;
        }
    }
    int c = jt * 16 + (lane & 15);
    int koff = kt * 32 + (lane >> 4) * 8;
    unsigned hi[8], lo[8];
#pragma unroll
    for (int j = 0; j < 8; j++) {
        int k = koff + j;
        float f = qkvmode ? src[(c >> 6) * 4096 + k * 64 + (c & 63)]
                          : src[k * 64 + c];
        unsigned u = __float_as_uint(f);
        hi[j] = u >> 16;
        float hf = __uint_as_float(u & 0xFFFF0000u);
        lo[j] = __float_as_uint(f - hf) >> 16;
    }
    int4 H, L;
    H.x = hi[0] | (hi[1] << 16); H.y = hi[2] | (hi[3] << 16);
    H.z = hi[4] | (hi[5] << 16); H.w = hi[6] | (hi[7] << 16);
    L.x = lo[0] | (lo[1] << 16); L.y = lo[2] | (lo[3] << 16);
    L.z = lo[4] | (lo[5] << 16); L.w = lo[6] | (lo[7] << 16);
    dst[lane] = H;
    dst[64 + lane] = L;
}

// ---------------- CSR build ----------------
__global__ __launch_bounds__(256) void k_hist(const int* __restrict__ dst,
                                              int* __restrict__ deg, int E) {
    int e = blockIdx.x * 256 + threadIdx.x;
    if (e < E) atomicAdd(&deg[dst[e]], 1);
}

__global__ __launch_bounds__(256) void k_scan1(const int* __restrict__ deg,
                                               int* __restrict__ excl,
                                               int* __restrict__ bsum, int n) {
    __shared__ int s[256];
    int t = threadIdx.x;
    int i = blockIdx.x * 256 + t;
    int v = (i < n) ? deg[i] : 0;
    s[t] = v;
    __syncthreads();
    for (int off = 1; off < 256; off <<= 1) {
        int a = (t >= off) ? s[t - off] : 0;
        __syncthreads();
        s[t] += a;
        __syncthreads();
    }
    if (i < n) excl[i] = s[t] - v;
    if (t == 255) bsum[blockIdx.x] = s[255];
}

__global__ __launch_bounds__(512) void k_scan2(int* __restrict__ bsum, int nb) {
    __shared__ int s[512];
    int t = threadIdx.x;
    int v = (t < nb) ? bsum[t] : 0;
    s[t] = v;
    __syncthreads();
    for (int off = 1; off < 512; off <<= 1) {
        int a = (t >= off) ? s[t - off] : 0;
        __syncthreads();
        s[t] += a;
        __syncthreads();
    }
    if (t < nb) bsum[t] = s[t] - v;  // exclusive
}

__global__ __launch_bounds__(256) void k_scan3(const int* __restrict__ excl,
                                               const int* __restrict__ bsum,
                                               int* __restrict__ row,
                                               int* __restrict__ cursor,
                                               int n, int E) {
    int i = blockIdx.x * 256 + threadIdx.x;
    if (i < n) {
        int r = excl[i] + bsum[blockIdx.x];
        row[i] = r;
        cursor[i] = r;
    }
    if (blockIdx.x == 0 && threadIdx.x == 0) row[n] = E;
}

__global__ __launch_bounds__(256) void k_scatter(const int* __restrict__ src,
                                                 const int* __restrict__ dst,
                                                 const float* __restrict__ ea,
                                                 int* __restrict__ cursor,
                                                 int2* __restrict__ ep, int E) {
    int e = blockIdx.x * 256 + threadIdx.x;
    if (e >= E) return;
    int d = dst[e];
    int p = atomicAdd(&cursor[d], 1);
    ep[p] = make_int2(src[e], __float_as_int(ea[e]));
}

// ---------------- fused input + layer-0 qkv (MFMA) ----------------
__global__ __launch_bounds__(256) void k_in_qkv(
    const float* __restrict__ x, const int4* __restrict__ pk_in,
    const float* __restrict__ b, const float* __restrict__ g,
    const float* __restrict__ be, const int4* __restrict__ pk_qkv,
    const float* __restrict__ bn, float* __restrict__ h,
    float* __restrict__ q, float* __restrict__ kvout, int n) {
    __shared__ float lds[4][1088];  // 16 rows x 68 (padded) per wave
    int lane = threadIdx.x & 63, wid = threadIdx.x >> 6;
    int nb = (blockIdx.x * 4 + wid) * 16;
    if (nb >= n) return;
    int g16 = lane >> 4, c16 = lane & 15;
    // A-frag from x (K=32, single ktile)
    int arow = min(nb + c16, n - 1);
    const float* xp = x + (size_t)arow * 32 + g16 * 8;
    float4 f0 = *(const float4*)xp;
    float4 f1 = *(const float4*)(xp + 4);
    bf16x8 ahi, alo;
    cvt_frag(f0, f1, ahi, alo);
    // GEMM1: x @ in_W
    float gv[4][4];  // [jt][r]
#pragma unroll
    for (int jt = 0; jt < 4; jt++) {
        f32x4 a = {0.f, 0.f, 0.f, 0.f};
        a = mm3(ahi, alo, pk_in, jt, lane, a);
        float bb = b[jt * 16 + c16];
#pragma unroll
        for (int r = 0; r < 4; r++) gv[jt][r] = gelu_f(a[r] + bb);
    }
    float gl[4], bel[4];
#pragma unroll
    for (int jt = 0; jt < 4; jt++) {
        gl[jt] = g[jt * 16 + c16];
        bel[jt] = be[jt * 16 + c16];
    }
    // LN per node (row r within group)
    float hreg[4][4];
#pragma unroll
    for (int r = 0; r < 4; r++) {
        float s = gv[0][r] + gv[1][r] + gv[2][r] + gv[3][r];
        float mu = sum16(s) * (1.0f / 64.0f);
        float vs = 0.f;
#pragma unroll
        for (int jt = 0; jt < 4; jt++) {
            float d = gv[jt][r] - mu;
            vs += d * d;
        }
        float var = sum16(vs) * (1.0f / 64.0f);
        float rs = rsqrtf(var + 1e-5f);
#pragma unroll
        for (int jt = 0; jt < 4; jt++)
            hreg[jt][r] = (gv[jt][r] - mu) * rs * gl[jt] + bel[jt];
    }
    // store h + stage into LDS for transpose
#pragma unroll
    for (int jt = 0; jt < 4; jt++)
#pragma unroll
        for (int r = 0; r < 4; r++) {
            int nd = nb + g16 * 4 + r;
            if (nd < n) h[(size_t)nd * 64 + jt * 16 + c16] = hreg[jt][r];
            lds[wid][(g16 * 4 + r) * 68 + jt * 16 + c16] = hreg[jt][r];
        }
    // A-frags of h (K=64) via LDS transpose
    bf16x8 qahi[2], qalo[2];
#pragma unroll
    for (int kt = 0; kt < 2; kt++) {
        const float* lp = &lds[wid][c16 * 68 + kt * 32 + g16 * 8];
        float4 t0 = *(const float4*)lp;
        float4 t1 = *(const float4*)(lp + 4);
        cvt_frag(t0, t1, qahi[kt], qalo[kt]);
    }
    // GEMM2: h @ [Wq|Wk|Wv]
#pragma unroll
    for (int jt = 0; jt < 12; jt++) {
        f32x4 a = {0.f, 0.f, 0.f, 0.f};
#pragma unroll
        for (int kt = 0; kt < 2; kt++) a = mm3(qahi[kt], qalo[kt], pk_qkv, jt * 2 + kt, lane, a);
        int c = jt * 16 + c16;
        float bias = bn[c];
        int m = c >> 6, cc = c & 63;
#pragma unroll
        for (int r = 0; r < 4; r++) {
            int nd = nb + g16 * 4 + r;
            if (nd < n) {
                float val = a[r] + bias;
                if (m == 0) q[(size_t)nd * 64 + cc] = val;
                else kvout[(size_t)nd * 128 + (m - 1) * 64 + cc] = val;
            }
        }
    }
}

// ---------------- attention (unchanged structure) ----------------
__global__ __launch_bounds__(256) void k_attn(
    const float* __restrict__ q, const float* __restrict__ kv,
    const int* __restrict__ row, const int2* __restrict__ ep,
    const float* __restrict__ We, float* __restrict__ out, int n) {
    int lane = threadIdx.x & 63;
    int node = blockIdx.x * 4 + (threadIdx.x >> 6);
    if (node >= n) return;
    int g = lane >> 4;
    int c16 = lane & 15;
    float4 qv = *(const float4*)(q + (size_t)node * 64 + c16 * 4);
    float4 wv = *(const float4*)(We + c16 * 4);
    int beg = row[node], end = row[node + 1];
    float m = -FLT_MAX, den = 0.f;
    float4 acc = {0.f, 0.f, 0.f, 0.f};
    for (int pos = beg; pos < end; pos += 4) {
        int idx = pos + g;
        bool valid = idx < end;
        int safe = valid ? idx : beg;
        int2 pr = ep[safe];
        int s = pr.x;
        float a = __int_as_float(pr.y);
        const float4* kp = (const float4*)(kv + (size_t)s * 128);
        float4 kq = kp[c16];
        float4 vq = kp[16 + c16];
        float p = qv.x * fmaf(a, wv.x, kq.x) + qv.y * fmaf(a, wv.y, kq.y) +
                  qv.z * fmaf(a, wv.z, kq.z) + qv.w * fmaf(a, wv.w, kq.w);
        p = dpp_add<0xB1, 0xF>(p);
        p = dpp_add<0x4E, 0xF>(p);
        float alpha = valid ? p * 0.25f : -FLT_MAX;
        float nm = fmaxf(m, alpha);
        float sc = __expf(m - nm);
        float ex = valid ? __expf(alpha - nm) : 0.f;
        den = fmaf(den, sc, ex);
        acc.x = fmaf(acc.x, sc, ex * fmaf(a, wv.x, vq.x));
        acc.y = fmaf(acc.y, sc, ex * fmaf(a, wv.y, vq.y));
        acc.z = fmaf(acc.z, sc, ex * fmaf(a, wv.z, vq.z));
        acc.w = fmaf(acc.w, sc, ex * fmaf(a, wv.w, vq.w));
        m = nm;
    }
#pragma unroll
    for (int mask = 16; mask <= 32; mask <<= 1) {
        float m2 = __shfl_xor(m, mask, 64);
        float d2 = __shfl_xor(den, mask, 64);
        float ax = __shfl_xor(acc.x, mask, 64);
        float ay = __shfl_xor(acc.y, mask, 64);
        float az = __shfl_xor(acc.z, mask, 64);
        float aw = __shfl_xor(acc.w, mask, 64);
        float nm = fmaxf(m, m2);
        float s1 = __expf(m - nm), s2 = __expf(m2 - nm);
        den = den * s1 + d2 * s2;
        acc.x = acc.x * s1 + ax * s2;
        acc.y = acc.y * s1 + ay * s2;
        acc.z = acc.z * s1 + az * s2;
        acc.w = acc.w * s1 + aw * s2;
        m = nm;
    }
    if (g == 0) {
        float inv = 1.0f / (den + 1e-16f);
        float4 o = {acc.x * inv, acc.y * inv, acc.z * inv, acc.w * inv};
        *(float4*)(out + (size_t)node * 64 + c16 * 4) = o;
    }
}

// ---------------- fused node update + next-layer qkv (MFMA) ----------------
template <int DO_QKV>
__global__ __launch_bounds__(256) void k_node_qkv(
    float* __restrict__ h, const float* __restrict__ o_in,
    const int4* __restrict__ pk_skip, const float* __restrict__ bs,
    const float* __restrict__ Wb, const float* __restrict__ lg,
    const float* __restrict__ lb, const int4* __restrict__ pk_qkv,
    const float* __restrict__ bn, float* __restrict__ q,
    float* __restrict__ kvout, int n) {
    __shared__ float lds[4][DO_QKV ? 1088 : 4];
    int lane = threadIdx.x & 63, wid = threadIdx.x >> 6;
    int nb = (blockIdx.x * 4 + wid) * 16;
    if (nb >= n) return;
    int g16 = lane >> 4, c16 = lane & 15;
    // A-frags of h_old (K=64)
    bf16x8 ahi[2], alo[2];
    int arow = min(nb + c16, n - 1);
#pragma unroll
    for (int kt = 0; kt < 2; kt++) {
        const float* hp = h + (size_t)arow * 64 + kt * 32 + g16 * 8;
        float4 f0 = *(const float4*)hp;
        float4 f1 = *(const float4*)(hp + 4);
        cvt_frag(f0, f1, ahi[kt], alo[kt]);
    }
    // skip GEMM: xr = h @ W_skip + bs
    float xr[4][4];
#pragma unroll
    for (int jt = 0; jt < 4; jt++) {
        f32x4 a = {0.f, 0.f, 0.f, 0.f};
#pragma unroll
        for (int kt = 0; kt < 2; kt++) a = mm3(ahi[kt], alo[kt], pk_skip, jt * 2 + kt, lane, a);
        float bias = bs[jt * 16 + c16];
#pragma unroll
        for (int r = 0; r < 4; r++) xr[jt][r] = a[r] + bias;
    }
    // load o (attention out) and h_old in C layout
    float ov[4][4], hold[4][4];
#pragma unroll
    for (int jt = 0; jt < 4; jt++)
#pragma unroll
        for (int r = 0; r < 4; r++) {
            int nd = min(nb + g16 * 4 + r, n - 1);
            ov[jt][r] = o_in[(size_t)nd * 64 + jt * 16 + c16];
            hold[jt][r] = h[(size_t)nd * 64 + jt * 16 + c16];
        }
    float wb0[4], wb1[4], wb2[4], lgv[4], lbv[4];
#pragma unroll
    for (int jt = 0; jt < 4; jt++) {
        int c = jt * 16 + c16;
        wb0[jt] = Wb[c]; wb1[jt] = Wb[64 + c]; wb2[jt] = Wb[128 + c];
        lgv[jt] = lg[c]; lbv[jt] = lb[c];
    }
    // beta gate + gelu + residual + LN
    float hnew[4][4];
#pragma unroll
    for (int r = 0; r < 4; r++) {
        float cbs = 0.f;
#pragma unroll
        for (int jt = 0; jt < 4; jt++)
            cbs += ov[jt][r] * wb0[jt] + xr[jt][r] * wb1[jt] +
                   (ov[jt][r] - xr[jt][r]) * wb2[jt];
        float cb = sum16(cbs);
        float beta = 1.0f / (1.0f + expf(-cb));
        float gvr[4], s = 0.f;
#pragma unroll
        for (int jt = 0; jt < 4; jt++) {
            float o2 = fmaf(beta, xr[jt][r] - ov[jt][r], ov[jt][r]);
            gvr[jt] = gelu_f(o2) + hold[jt][r];
            s += gvr[jt];
        }
        float mu = sum16(s) * (1.0f / 64.0f);
        float vs = 0.f;
#pragma unroll
        for (int jt = 0; jt < 4; jt++) {
            float d = gvr[jt] - mu;
            vs += d * d;
        }
        float var = sum16(vs) * (1.0f / 64.0f);
        float rs = rsqrtf(var + 1e-5f);
#pragma unroll
        for (int jt = 0; jt < 4; jt++)
            hnew[jt][r] = (gvr[jt] - mu) * rs * lgv[jt] + lbv[jt];
    }
    // store h_new (+ LDS stage for transpose)
#pragma unroll
    for (int jt = 0; jt < 4; jt++)
#pragma unroll
        for (int r = 0; r < 4; r++) {
            int nd = nb + g16 * 4 + r;
            if (nd < n) h[(size_t)nd * 64 + jt * 16 + c16] = hnew[jt][r];
            if (DO_QKV) lds[wid][(g16 * 4 + r) * 68 + jt * 16 + c16] = hnew[jt][r];
        }
    if (!DO_QKV) return;
    bf16x8 qahi[2], qalo[2];
#pragma unroll
    for (int kt = 0; kt < 2; kt++) {
        const float* lp = &lds[wid][c16 * 68 + kt * 32 + g16 * 8];
        float4 t0 = *(const float4*)lp;
        float4 t1 = *(const float4*)(lp + 4);
        cvt_frag(t0, t1, qahi[kt], qalo[kt]);
    }
#pragma unroll
    for (int jt = 0; jt < 12; jt++) {
        f32x4 a = {0.f, 0.f, 0.f, 0.f};
#pragma unroll
        for (int kt = 0; kt < 2; kt++) a = mm3(qahi[kt], qalo[kt], pk_qkv, jt * 2 + kt, lane, a);
        int c = jt * 16 + c16;
        float bias = bn[c];
        int m = c >> 6, cc = c & 63;
#pragma unroll
        for (int r = 0; r < 4; r++) {
            int nd = nb + g16 * 4 + r;
            if (nd < n) {
                float val = a[r] + bias;
                if (m == 0) q[(size_t)nd * 64 + cc] = val;
                else kvout[(size_t)nd * 128 + (m - 1) * 64 + cc] = val;
            }
        }
    }
}

// pooling: wave-per-chunk over sorted batch; flush per graph-run
__global__ __launch_bounds__(256) void k_pool3(
    const float* __restrict__ h, const int* __restrict__ batch,
    float* __restrict__ gsum, unsigned int* __restrict__ gmax,
    float* __restrict__ cnt, int n, int chunk) {
    int wave = (blockIdx.x * 256 + threadIdx.x) >> 6;
    int lane = threadIdx.x & 63;
    int i0 = wave * chunk;
    if (i0 >= n) return;
    int i1 = min(n, i0 + chunk);
    int cur = batch[i0];
    float s = 0.f, mx = -FLT_MAX;
    int run = 0;
    for (int i = i0; i < i1; ++i) {
        int g = batch[i];
        if (g != cur) {
            atomicAdd(gsum + cur * 64 + lane, s);
            atomicMax(gmax + cur * 64 + lane, f2mono(mx));
            if (lane == 0) atomicAdd(cnt + cur, (float)run);
            s = 0.f; mx = -FLT_MAX; run = 0; cur = g;
        }
        float v = h[(size_t)i * 64 + lane];
        s += v;
        mx = fmaxf(mx, v);
        ++run;
    }
    atomicAdd(gsum + cur * 64 + lane, s);
    atomicMax(gmax + cur * 64 + lane, f2mono(mx));
    if (lane == 0) atomicAdd(cnt + cur, (float)run);
}

__global__ void k_final(const float* __restrict__ gsum,
                        const unsigned int* __restrict__ gmax,
                        const float* __restrict__ cnt,
                        const float* __restrict__ W1, const float* __restrict__ b1,
                        const float* __restrict__ W2, const float* __restrict__ b2,
                        const float* __restrict__ W3, const float* __restrict__ b3,
                        float* __restrict__ out) {
    int g = blockIdx.x;
    int lane = threadIdx.x;
    __shared__ float rep[128];
    __shared__ float t1[64];
    __shared__ float t2[32];
    float c = fmaxf(cnt[g], 1.0f);
    rep[lane] = gsum[g * 64 + lane] / c;
    rep[64 + lane] = mono2f(gmax[g * 64 + lane]);
    __syncthreads();
    float a = b1[lane];
#pragma unroll 8
    for (int i = 0; i < 128; i++) a = fmaf(rep[i], W1[i * 64 + lane], a);
    t1[lane] = gelu_f(a);
    __syncthreads();
    if (lane < 32) {
        float a2 = b2[lane];
#pragma unroll 8
        for (int i = 0; i < 64; i++) a2 = fmaf(t1[i], W2[i * 32 + lane], a2);
        t2[lane] = gelu_f(a2);
    }
    __syncthreads();
    if (lane < 32) {
        float p = t2[lane] * W3[lane];
#pragma unroll
        for (int o = 16; o > 0; o >>= 1) p += __shfl_xor(p, o, 64);
        if (lane == 0) out[g] = p + b3[0];
    }
}

extern "C" void kernel_launch(void* const* d_in, const int* in_sizes, int n_in,
                              void* d_out, int out_size, void* d_ws,
                              size_t ws_size, hipStream_t stream) {
    const float* x      = (const float*)d_in[0];
    const int*   eidx   = (const int*)d_in[1];
    const float* ea     = (const float*)d_in[2];
    const int*   batch  = (const int*)d_in[3];
    const float* in_W   = (const float*)d_in[4];
    const float* in_b   = (const float*)d_in[5];
    const float* in_lng = (const float*)d_in[6];
    const float* in_lnb = (const float*)d_in[7];
    const float* W_qkv  = (const float*)d_in[8];
    const float* b_qkv  = (const float*)d_in[9];
    const float* W_edge = (const float*)d_in[10];
    const float* W_skip = (const float*)d_in[11];
    const float* b_skip = (const float*)d_in[12];
    const float* W_beta = (const float*)d_in[13];
    const float* ln_g   = (const float*)d_in[14];
    const float* ln_b   = (const float*)d_in[15];
    const float* r1_W   = (const float*)d_in[16];
    const float* r1_b   = (const float*)d_in[17];
    const float* r2_W   = (const float*)d_in[18];
    const float* r2_b   = (const float*)d_in[19];
    const float* r3_W   = (const float*)d_in[20];
    const float* r3_b   = (const float*)d_in[21];

    int n = in_sizes[0] / 32;
    int E = in_sizes[2];
    const int* src = eidx;
    const int* dst = eidx + E;

    char* ws = (char*)d_ws;
    size_t off = 0;
    auto alloc = [&](size_t bytes) -> void* {
        void* p = ws + off;
        off = (off + bytes + 255) & ~(size_t)255;
        return p;
    };
    float* h    = (float*)alloc((size_t)n * 64 * 4);
    float* q    = (float*)alloc((size_t)n * 64 * 4);
    float* kv   = (float*)alloc((size_t)n * 128 * 4);
    float* oacc = (float*)alloc((size_t)n * 64 * 4);
    int* deg    = (int*)alloc((size_t)n * 4);
    int* excl   = (int*)alloc((size_t)n * 4);
    int* bsum   = (int*)alloc(512 * 4);
    int* row    = (int*)alloc((size_t)(n + 1) * 4);
    int* cursor = (int*)alloc((size_t)n * 4);
    int2* ep    = (int2*)alloc((size_t)E * 8);
    int4* pk_in   = (int4*)alloc(4 * 128 * 16);
    int4* pk_skip = (int4*)alloc(3 * 8 * 128 * 16);
    int4* pk_qkv  = (int4*)alloc((size_t)3 * 24 * 128 * 16);
    float* gsum = (float*)alloc((NGRAPH * 64 * 2 + NGRAPH) * 4);
    unsigned int* gmax = (unsigned int*)(gsum + NGRAPH * 64);
    float* cnt  = gsum + NGRAPH * 128;

    int nb4 = (n + 3) / 4;
    int nb64 = (n + 63) / 64;
    int nbs = (n + 255) / 256;
    int ebs = (E + 255) / 256;

    // weight packing + CSR build
    k_cvt<<<25, 256, 0, stream>>>(in_W, W_skip, W_qkv, pk_in, pk_skip, pk_qkv);
    hipMemsetAsync(deg, 0, (size_t)n * 4, stream);
    k_hist<<<ebs, 256, 0, stream>>>(dst, deg, E);
    k_scan1<<<nbs, 256, 0, stream>>>(deg, excl, bsum, n);
    k_scan2<<<1, 512, 0, stream>>>(bsum, nbs);
    k_scan3<<<nbs, 256, 0, stream>>>(excl, bsum, row, cursor, n, E);
    k_scatter<<<ebs, 256, 0, stream>>>(src, dst, ea, cursor, ep, E);

    k_in_qkv<<<nb64, 256, 0, stream>>>(x, pk_in, in_b, in_lng, in_lnb,
                                       pk_qkv, b_qkv, h, q, kv, n);

    for (int l = 0; l < LAYERS; l++) {
        k_attn<<<nb4, 256, 0, stream>>>(q, kv, row, ep, W_edge + l * 64, oacc, n);
        if (l + 1 < LAYERS) {
            k_node_qkv<1><<<nb64, 256, 0, stream>>>(
                h, oacc, pk_skip + l * 8 * 128, b_skip + l * 64,
                W_beta + l * 192, ln_g + l * 64, ln_b + l * 64,
                pk_qkv + (size_t)(l + 1) * 24 * 128, b_qkv + (size_t)(l + 1) * 192,
                q, kv, n);
        } else {
            k_node_qkv<0><<<nb64, 256, 0, stream>>>(
                h, oacc, pk_skip + l * 8 * 128, b_skip + l * 64,
                W_beta + l * 192, ln_g + l * 64, ln_b + l * 64,
                nullptr, nullptr, nullptr, nullptr, n);
        }
    }

    hipMemsetAsync(gsum, 0, (NGRAPH * 64 * 2 + NGRAPH) * 4, stream);
    int nwaves = 4096;
    int chunk = (n + nwaves - 1) / nwaves;
    k_pool3<<<nwaves / 4, 256, 0, stream>>>(h, batch, gsum, gmax, cnt, n, chunk);
    k_final<<<NGRAPH, 64, 0, stream>>>(gsum, gmax, cnt, r1_W, r1_b, r2_W, r2_b,
                                       r3_W, r3_b, (float*)d_out);
}

// Round 6
// 394.061 us; speedup vs baseline: 27.2313x; 1.1330x over previous
//
#include <hip/hip_runtime.h>
#include <hip/hip_fp16.h>
#include <math.h>
#include <float.h>

#define LAYERS 3
#define NGRAPH 128

typedef __attribute__((ext_vector_type(8))) short bf16x8;
typedef __attribute__((ext_vector_type(4))) float f32x4;

union bfr { int4 i; bf16x8 b; };

__device__ __forceinline__ float gelu_f(float x) {
    return 0.5f * x * (1.0f + erff(x * 0.70710678118654752440f));
}

// x + dpp_perm(x); masked rows add 0 (old=0, bound_ctrl=false)
template <int CTRL, int RMASK>
__device__ __forceinline__ float dpp_add(float x) {
    int t = __builtin_amdgcn_update_dpp(0, __float_as_int(x), CTRL, RMASK, 0xF, false);
    return x + __int_as_float(t);
}

// sum over each 16-lane group (row); result in all 16 lanes
__device__ __forceinline__ float sum16(float v) {
    v = dpp_add<0xB1, 0xF>(v);   // quad_perm xor1
    v = dpp_add<0x4E, 0xF>(v);   // quad_perm xor2
    v = dpp_add<0x141, 0xF>(v);  // row_half_mirror
    v = dpp_add<0x140, 0xF>(v);  // row_mirror
    return v;
}

__device__ __forceinline__ unsigned int f2mono(float f) {
    unsigned int u = __float_as_uint(f);
    return (u & 0x80000000u) ? ~u : (u | 0x80000000u);
}
__device__ __forceinline__ float mono2f(unsigned int u) {
    return (u & 0x80000000u) ? __uint_as_float(u ^ 0x80000000u)
                             : __uint_as_float(~u);
}

__device__ __forceinline__ float2 h2f2(int bits) {
    __half2 h = *reinterpret_cast<__half2*>(&bits);
    return __half22float2(h);
}

// split-bf16 fragment build: hi = trunc-bf16(x), lo = trunc-bf16(x - hi)
__device__ __forceinline__ void cvt_frag(const float4& f0, const float4& f1,
                                         bf16x8& hi, bf16x8& lo) {
    float ff[8] = {f0.x, f0.y, f0.z, f0.w, f1.x, f1.y, f1.z, f1.w};
#pragma unroll
    for (int j = 0; j < 8; j++) {
        unsigned u = __float_as_uint(ff[j]);
        hi[j] = (short)(u >> 16);
        float hf = __uint_as_float(u & 0xFFFF0000u);
        lo[j] = (short)(__float_as_uint(ff[j] - hf) >> 16);
    }
}

// acc += A * B_tile with 3-term split (drops lo*lo, ~2^-16 relative)
__device__ __forceinline__ f32x4 mm3(const bf16x8& ahi, const bf16x8& alo,
                                     const int4* __restrict__ pk, int tile,
                                     int lane, f32x4 acc) {
    bfr bh, bl;
    bh.i = pk[tile * 128 + lane];
    bl.i = pk[tile * 128 + 64 + lane];
    acc = __builtin_amdgcn_mfma_f32_16x16x32_bf16(alo, bh.b, acc, 0, 0, 0);
    acc = __builtin_amdgcn_mfma_f32_16x16x32_bf16(ahi, bl.b, acc, 0, 0, 0);
    acc = __builtin_amdgcn_mfma_f32_16x16x32_bf16(ahi, bh.b, acc, 0, 0, 0);
    return acc;
}

// ---------------- weight packing (once per launch) ----------------
__global__ __launch_bounds__(256) void k_cvt(
    const float* __restrict__ in_W, const float* __restrict__ W_skip,
    const float* __restrict__ W_qkv, int4* __restrict__ pk_in,
    int4* __restrict__ pk_skip, int4* __restrict__ pk_qkv) {
    int w = (blockIdx.x * 256 + threadIdx.x) >> 6;
    if (w >= 100) return;
    int lane = threadIdx.x & 63;
    const float* src;
    int4* dst;
    int kt, jt, qkvmode = 0;
    if (w < 4) {
        kt = 0; jt = w;
        src = in_W;
        dst = pk_in + w * 128;
    } else {
        int l = (w - 4) >> 5, r = (w - 4) & 31;
        if (r < 8) {
            kt = r & 1; jt = r >> 1;
            src = W_skip + l * 4096;
            dst = pk_skip + (l * 8 + r) * 128;
        } else {
            int tq = r - 8;
            kt = tq & 1; jt = tq >> 1;
            src = W_qkv + l * 12288;
            dst = pk_qkv + (l * 24 + tq) * 128;
            qkvmode = 1;
        }
    }
    int c = jt * 16 + (lane & 15);
    int koff = kt * 32 + (lane >> 4) * 8;
    unsigned hi[8], lo[8];
#pragma unroll
    for (int j = 0; j < 8; j++) {
        int k = koff + j;
        float f = qkvmode ? src[(c >> 6) * 4096 + k * 64 + (c & 63)]
                          : src[k * 64 + c];
        unsigned u = __float_as_uint(f);
        hi[j] = u >> 16;
        float hf = __uint_as_float(u & 0xFFFF0000u);
        lo[j] = __float_as_uint(f - hf) >> 16;
    }
    int4 H, L;
    H.x = hi[0] | (hi[1] << 16); H.y = hi[2] | (hi[3] << 16);
    H.z = hi[4] | (hi[5] << 16); H.w = hi[6] | (hi[7] << 16);
    L.x = lo[0] | (lo[1] << 16); L.y = lo[2] | (lo[3] << 16);
    L.z = lo[4] | (lo[5] << 16); L.w = lo[6] | (lo[7] << 16);
    dst[lane] = H;
    dst[64 + lane] = L;
}

// ---------------- CSR build ----------------
__global__ __launch_bounds__(256) void k_hist(const int* __restrict__ dst,
                                              int* __restrict__ deg, int E) {
    int e = blockIdx.x * 256 + threadIdx.x;
    if (e < E) atomicAdd(&deg[dst[e]], 1);
}

__global__ __launch_bounds__(256) void k_scan1(const int* __restrict__ deg,
                                               int* __restrict__ excl,
                                               int* __restrict__ bsum, int n) {
    __shared__ int s[256];
    int t = threadIdx.x;
    int i = blockIdx.x * 256 + t;
    int v = (i < n) ? deg[i] : 0;
    s[t] = v;
    __syncthreads();
    for (int off = 1; off < 256; off <<= 1) {
        int a = (t >= off) ? s[t - off] : 0;
        __syncthreads();
        s[t] += a;
        __syncthreads();
    }
    if (i < n) excl[i] = s[t] - v;
    if (t == 255) bsum[blockIdx.x] = s[255];
}

__global__ __launch_bounds__(512) void k_scan2(int* __restrict__ bsum, int nb) {
    __shared__ int s[512];
    int t = threadIdx.x;
    int v = (t < nb) ? bsum[t] : 0;
    s[t] = v;
    __syncthreads();
    for (int off = 1; off < 512; off <<= 1) {
        int a = (t >= off) ? s[t - off] : 0;
        __syncthreads();
        s[t] += a;
        __syncthreads();
    }
    if (t < nb) bsum[t] = s[t] - v;  // exclusive
}

__global__ __launch_bounds__(256) void k_scan3(const int* __restrict__ excl,
                                               const int* __restrict__ bsum,
                                               int* __restrict__ row,
                                               int* __restrict__ cursor,
                                               int n, int E) {
    int i = blockIdx.x * 256 + threadIdx.x;
    if (i < n) {
        int r = excl[i] + bsum[blockIdx.x];
        row[i] = r;
        cursor[i] = r;
    }
    if (blockIdx.x == 0 && threadIdx.x == 0) row[n] = E;
}

__global__ __launch_bounds__(256) void k_scatter(const int* __restrict__ src,
                                                 const int* __restrict__ dst,
                                                 const float* __restrict__ ea,
                                                 int* __restrict__ cursor,
                                                 int2* __restrict__ ep, int E) {
    int e = blockIdx.x * 256 + threadIdx.x;
    if (e >= E) return;
    int d = dst[e];
    int p = atomicAdd(&cursor[d], 1);
    ep[p] = make_int2(src[e], __float_as_int(ea[e]));
}

// ---------------- fused input + layer-0 qkv (MFMA) ----------------
__global__ __launch_bounds__(256) void k_in_qkv(
    const float* __restrict__ x, const int4* __restrict__ pk_in,
    const float* __restrict__ b, const float* __restrict__ g,
    const float* __restrict__ be, const int4* __restrict__ pk_qkv,
    const float* __restrict__ bn, float* __restrict__ h,
    float* __restrict__ q, __half* __restrict__ kvout, int n) {
    __shared__ float lds[4][1088];  // 16 rows x 68 (padded) per wave
    int lane = threadIdx.x & 63, wid = threadIdx.x >> 6;
    int nb = (blockIdx.x * 4 + wid) * 16;
    if (nb >= n) return;
    int g16 = lane >> 4, c16 = lane & 15;
    int arow = min(nb + c16, n - 1);
    const float* xp = x + (size_t)arow * 32 + g16 * 8;
    float4 f0 = *(const float4*)xp;
    float4 f1 = *(const float4*)(xp + 4);
    bf16x8 ahi, alo;
    cvt_frag(f0, f1, ahi, alo);
    float gv[4][4];
#pragma unroll
    for (int jt = 0; jt < 4; jt++) {
        f32x4 a = {0.f, 0.f, 0.f, 0.f};
        a = mm3(ahi, alo, pk_in, jt, lane, a);
        float bb = b[jt * 16 + c16];
#pragma unroll
        for (int r = 0; r < 4; r++) gv[jt][r] = gelu_f(a[r] + bb);
    }
    float gl[4], bel[4];
#pragma unroll
    for (int jt = 0; jt < 4; jt++) {
        gl[jt] = g[jt * 16 + c16];
        bel[jt] = be[jt * 16 + c16];
    }
    float hreg[4][4];
#pragma unroll
    for (int r = 0; r < 4; r++) {
        float s = gv[0][r] + gv[1][r] + gv[2][r] + gv[3][r];
        float mu = sum16(s) * (1.0f / 64.0f);
        float vs = 0.f;
#pragma unroll
        for (int jt = 0; jt < 4; jt++) {
            float d = gv[jt][r] - mu;
            vs += d * d;
        }
        float var = sum16(vs) * (1.0f / 64.0f);
        float rs = rsqrtf(var + 1e-5f);
#pragma unroll
        for (int jt = 0; jt < 4; jt++)
            hreg[jt][r] = (gv[jt][r] - mu) * rs * gl[jt] + bel[jt];
    }
#pragma unroll
    for (int jt = 0; jt < 4; jt++)
#pragma unroll
        for (int r = 0; r < 4; r++) {
            int nd = nb + g16 * 4 + r;
            if (nd < n) h[(size_t)nd * 64 + jt * 16 + c16] = hreg[jt][r];
            lds[wid][(g16 * 4 + r) * 68 + jt * 16 + c16] = hreg[jt][r];
        }
    bf16x8 qahi[2], qalo[2];
#pragma unroll
    for (int kt = 0; kt < 2; kt++) {
        const float* lp = &lds[wid][c16 * 68 + kt * 32 + g16 * 8];
        float4 t0 = *(const float4*)lp;
        float4 t1 = *(const float4*)(lp + 4);
        cvt_frag(t0, t1, qahi[kt], qalo[kt]);
    }
#pragma unroll
    for (int jt = 0; jt < 12; jt++) {
        f32x4 a = {0.f, 0.f, 0.f, 0.f};
#pragma unroll
        for (int kt = 0; kt < 2; kt++) a = mm3(qahi[kt], qalo[kt], pk_qkv, jt * 2 + kt, lane, a);
        int c = jt * 16 + c16;
        float bias = bn[c];
        int m = c >> 6, cc = c & 63;
#pragma unroll
        for (int r = 0; r < 4; r++) {
            int nd = nb + g16 * 4 + r;
            if (nd < n) {
                float val = a[r] + bias;
                if (m == 0) q[(size_t)nd * 64 + cc] = val;
                else kvout[(size_t)nd * 128 + (m - 1) * 64 + cc] = __float2half(val);
            }
        }
    }
}

// ---------------- attention: fp16 kv gathers ----------------
__global__ __launch_bounds__(256) void k_attn(
    const float* __restrict__ q, const __half* __restrict__ kv,
    const int* __restrict__ row, const int2* __restrict__ ep,
    const float* __restrict__ We, float* __restrict__ out, int n) {
    int lane = threadIdx.x & 63;
    int node = blockIdx.x * 4 + (threadIdx.x >> 6);
    if (node >= n) return;
    int g = lane >> 4;
    int c16 = lane & 15;
    float4 qv = *(const float4*)(q + (size_t)node * 64 + c16 * 4);
    float4 wv = *(const float4*)(We + c16 * 4);
    int beg = row[node], end = row[node + 1];
    float m = -FLT_MAX, den = 0.f;
    float4 acc = {0.f, 0.f, 0.f, 0.f};
    for (int pos = beg; pos < end; pos += 4) {
        int idx = pos + g;
        bool valid = idx < end;
        int safe = valid ? idx : beg;
        int2 pr = ep[safe];
        int s = pr.x;
        float a = __int_as_float(pr.y);
        const __half* kp = kv + (size_t)s * 128 + c16 * 4;
        int2 kb = *(const int2*)kp;
        int2 vb = *(const int2*)(kp + 64);
        float2 k01 = h2f2(kb.x), k23 = h2f2(kb.y);
        float2 v01 = h2f2(vb.x), v23 = h2f2(vb.y);
        float p = qv.x * fmaf(a, wv.x, k01.x) + qv.y * fmaf(a, wv.y, k01.y) +
                  qv.z * fmaf(a, wv.z, k23.x) + qv.w * fmaf(a, wv.w, k23.y);
        p = dpp_add<0xB1, 0xF>(p);
        p = dpp_add<0x4E, 0xF>(p);
        float alpha = valid ? p * 0.25f : -FLT_MAX;
        float nm = fmaxf(m, alpha);
        float sc = __expf(m - nm);
        float ex = valid ? __expf(alpha - nm) : 0.f;
        den = fmaf(den, sc, ex);
        acc.x = fmaf(acc.x, sc, ex * fmaf(a, wv.x, v01.x));
        acc.y = fmaf(acc.y, sc, ex * fmaf(a, wv.y, v01.y));
        acc.z = fmaf(acc.z, sc, ex * fmaf(a, wv.z, v23.x));
        acc.w = fmaf(acc.w, sc, ex * fmaf(a, wv.w, v23.y));
        m = nm;
    }
#pragma unroll
    for (int mask = 16; mask <= 32; mask <<= 1) {
        float m2 = __shfl_xor(m, mask, 64);
        float d2 = __shfl_xor(den, mask, 64);
        float ax = __shfl_xor(acc.x, mask, 64);
        float ay = __shfl_xor(acc.y, mask, 64);
        float az = __shfl_xor(acc.z, mask, 64);
        float aw = __shfl_xor(acc.w, mask, 64);
        float nm = fmaxf(m, m2);
        float s1 = __expf(m - nm), s2 = __expf(m2 - nm);
        den = den * s1 + d2 * s2;
        acc.x = acc.x * s1 + ax * s2;
        acc.y = acc.y * s1 + ay * s2;
        acc.z = acc.z * s1 + az * s2;
        acc.w = acc.w * s1 + aw * s2;
        m = nm;
    }
    if (g == 0) {
        float inv = 1.0f / (den + 1e-16f);
        float4 o = {acc.x * inv, acc.y * inv, acc.z * inv, acc.w * inv};
        *(float4*)(out + (size_t)node * 64 + c16 * 4) = o;
    }
}

// ---------------- fused node update + next-layer qkv (MFMA) ----------------
template <int DO_QKV>
__global__ __launch_bounds__(256) void k_node_qkv(
    float* __restrict__ h, const float* __restrict__ o_in,
    const int4* __restrict__ pk_skip, const float* __restrict__ bs,
    const float* __restrict__ Wb, const float* __restrict__ lg,
    const float* __restrict__ lb, const int4* __restrict__ pk_qkv,
    const float* __restrict__ bn, float* __restrict__ q,
    __half* __restrict__ kvout, int n) {
    __shared__ float lds[4][DO_QKV ? 1088 : 4];
    int lane = threadIdx.x & 63, wid = threadIdx.x >> 6;
    int nb = (blockIdx.x * 4 + wid) * 16;
    if (nb >= n) return;
    int g16 = lane >> 4, c16 = lane & 15;
    bf16x8 ahi[2], alo[2];
    int arow = min(nb + c16, n - 1);
#pragma unroll
    for (int kt = 0; kt < 2; kt++) {
        const float* hp = h + (size_t)arow * 64 + kt * 32 + g16 * 8;
        float4 f0 = *(const float4*)hp;
        float4 f1 = *(const float4*)(hp + 4);
        cvt_frag(f0, f1, ahi[kt], alo[kt]);
    }
    float xr[4][4];
#pragma unroll
    for (int jt = 0; jt < 4; jt++) {
        f32x4 a = {0.f, 0.f, 0.f, 0.f};
#pragma unroll
        for (int kt = 0; kt < 2; kt++) a = mm3(ahi[kt], alo[kt], pk_skip, jt * 2 + kt, lane, a);
        float bias = bs[jt * 16 + c16];
#pragma unroll
        for (int r = 0; r < 4; r++) xr[jt][r] = a[r] + bias;
    }
    float ov[4][4], hold[4][4];
#pragma unroll
    for (int jt = 0; jt < 4; jt++)
#pragma unroll
        for (int r = 0; r < 4; r++) {
            int nd = min(nb + g16 * 4 + r, n - 1);
            ov[jt][r] = o_in[(size_t)nd * 64 + jt * 16 + c16];
            hold[jt][r] = h[(size_t)nd * 64 + jt * 16 + c16];
        }
    float wb0[4], wb1[4], wb2[4], lgv[4], lbv[4];
#pragma unroll
    for (int jt = 0; jt < 4; jt++) {
        int c = jt * 16 + c16;
        wb0[jt] = Wb[c]; wb1[jt] = Wb[64 + c]; wb2[jt] = Wb[128 + c];
        lgv[jt] = lg[c]; lbv[jt] = lb[c];
    }
    float hnew[4][4];
#pragma unroll
    for (int r = 0; r < 4; r++) {
        float cbs = 0.f;
#pragma unroll
        for (int jt = 0; jt < 4; jt++)
            cbs += ov[jt][r] * wb0[jt] + xr[jt][r] * wb1[jt] +
                   (ov[jt][r] - xr[jt][r]) * wb2[jt];
        float cb = sum16(cbs);
        float beta = 1.0f / (1.0f + expf(-cb));
        float gvr[4], s = 0.f;
#pragma unroll
        for (int jt = 0; jt < 4; jt++) {
            float o2 = fmaf(beta, xr[jt][r] - ov[jt][r], ov[jt][r]);
            gvr[jt] = gelu_f(o2) + hold[jt][r];
            s += gvr[jt];
        }
        float mu = sum16(s) * (1.0f / 64.0f);
        float vs = 0.f;
#pragma unroll
        for (int jt = 0; jt < 4; jt++) {
            float d = gvr[jt] - mu;
            vs += d * d;
        }
        float var = sum16(vs) * (1.0f / 64.0f);
        float rs = rsqrtf(var + 1e-5f);
#pragma unroll
        for (int jt = 0; jt < 4; jt++)
            hnew[jt][r] = (gvr[jt] - mu) * rs * lgv[jt] + lbv[jt];
    }
#pragma unroll
    for (int jt = 0; jt < 4; jt++)
#pragma unroll
        for (int r = 0; r < 4; r++) {
            int nd = nb + g16 * 4 + r;
            if (nd < n) h[(size_t)nd * 64 + jt * 16 + c16] = hnew[jt][r];
            if (DO_QKV) lds[wid][(g16 * 4 + r) * 68 + jt * 16 + c16] = hnew[jt][r];
        }
    if (!DO_QKV) return;
    bf16x8 qahi[2], qalo[2];
#pragma unroll
    for (int kt = 0; kt < 2; kt++) {
        const float* lp = &lds[wid][c16 * 68 + kt * 32 + g16 * 8];
        float4 t0 = *(const float4*)lp;
        float4 t1 = *(const float4*)(lp + 4);
        cvt_frag(t0, t1, qahi[kt], qalo[kt]);
    }
#pragma unroll
    for (int jt = 0; jt < 12; jt++) {
        f32x4 a = {0.f, 0.f, 0.f, 0.f};
#pragma unroll
        for (int kt = 0; kt < 2; kt++) a = mm3(qahi[kt], qalo[kt], pk_qkv, jt * 2 + kt, lane, a);
        int c = jt * 16 + c16;
        float bias = bn[c];
        int m = c >> 6, cc = c & 63;
#pragma unroll
        for (int r = 0; r < 4; r++) {
            int nd = nb + g16 * 4 + r;
            if (nd < n) {
                float val = a[r] + bias;
                if (m == 0) q[(size_t)nd * 64 + cc] = val;
                else kvout[(size_t)nd * 128 + (m - 1) * 64 + cc] = __float2half(val);
            }
        }
    }
}

// pooling: wave-per-chunk over sorted batch; flush per graph-run
__global__ __launch_bounds__(256) void k_pool3(
    const float* __restrict__ h, const int* __restrict__ batch,
    float* __restrict__ gsum, unsigned int* __restrict__ gmax,
    float* __restrict__ cnt, int n, int chunk) {
    int wave = (blockIdx.x * 256 + threadIdx.x) >> 6;
    int lane = threadIdx.x & 63;
    int i0 = wave * chunk;
    if (i0 >= n) return;
    int i1 = min(n, i0 + chunk);
    int cur = batch[i0];
    float s = 0.f, mx = -FLT_MAX;
    int run = 0;
    for (int i = i0; i < i1; ++i) {
        int g = batch[i];
        if (g != cur) {
            atomicAdd(gsum + cur * 64 + lane, s);
            atomicMax(gmax + cur * 64 + lane, f2mono(mx));
            if (lane == 0) atomicAdd(cnt + cur, (float)run);
            s = 0.f; mx = -FLT_MAX; run = 0; cur = g;
        }
        float v = h[(size_t)i * 64 + lane];
        s += v;
        mx = fmaxf(mx, v);
        ++run;
    }
    atomicAdd(gsum + cur * 64 + lane, s);
    atomicMax(gmax + cur * 64 + lane, f2mono(mx));
    if (lane == 0) atomicAdd(cnt + cur, (float)run);
}

__global__ void k_final(const float* __restrict__ gsum,
                        const unsigned int* __restrict__ gmax,
                        const float* __restrict__ cnt,
                        const float* __restrict__ W1, const float* __restrict__ b1,
                        const float* __restrict__ W2, const float* __restrict__ b2,
                        const float* __restrict__ W3, const float* __restrict__ b3,
                        float* __restrict__ out) {
    int g = blockIdx.x;
    int lane = threadIdx.x;
    __shared__ float rep[128];
    __shared__ float t1[64];
    __shared__ float t2[32];
    float c = fmaxf(cnt[g], 1.0f);
    rep[lane] = gsum[g * 64 + lane] / c;
    rep[64 + lane] = mono2f(gmax[g * 64 + lane]);
    __syncthreads();
    float a = b1[lane];
#pragma unroll 8
    for (int i = 0; i < 128; i++) a = fmaf(rep[i], W1[i * 64 + lane], a);
    t1[lane] = gelu_f(a);
    __syncthreads();
    if (lane < 32) {
        float a2 = b2[lane];
#pragma unroll 8
        for (int i = 0; i < 64; i++) a2 = fmaf(t1[i], W2[i * 32 + lane], a2);
        t2[lane] = gelu_f(a2);
    }
    __syncthreads();
    if (lane < 32) {
        float p = t2[lane] * W3[lane];
#pragma unroll
        for (int o = 16; o > 0; o >>= 1) p += __shfl_xor(p, o, 64);
        if (lane == 0) out[g] = p + b3[0];
    }
}

extern "C" void kernel_launch(void* const* d_in, const int* in_sizes, int n_in,
                              void* d_out, int out_size, void* d_ws,
                              size_t ws_size, hipStream_t stream) {
    const float* x      = (const float*)d_in[0];
    const int*   eidx   = (const int*)d_in[1];
    const float* ea     = (const float*)d_in[2];
    const int*   batch  = (const int*)d_in[3];
    const float* in_W   = (const float*)d_in[4];
    const float* in_b   = (const float*)d_in[5];
    const float* in_lng = (const float*)d_in[6];
    const float* in_lnb = (const float*)d_in[7];
    const float* W_qkv  = (const float*)d_in[8];
    const float* b_qkv  = (const float*)d_in[9];
    const float* W_edge = (const float*)d_in[10];
    const float* W_skip = (const float*)d_in[11];
    const float* b_skip = (const float*)d_in[12];
    const float* W_beta = (const float*)d_in[13];
    const float* ln_g   = (const float*)d_in[14];
    const float* ln_b   = (const float*)d_in[15];
    const float* r1_W   = (const float*)d_in[16];
    const float* r1_b   = (const float*)d_in[17];
    const float* r2_W   = (const float*)d_in[18];
    const float* r2_b   = (const float*)d_in[19];
    const float* r3_W   = (const float*)d_in[20];
    const float* r3_b   = (const float*)d_in[21];

    int n = in_sizes[0] / 32;
    int E = in_sizes[2];
    const int* src = eidx;
    const int* dst = eidx + E;

    char* ws = (char*)d_ws;
    size_t off = 0;
    auto alloc = [&](size_t bytes) -> void* {
        void* p = ws + off;
        off = (off + bytes + 255) & ~(size_t)255;
        return p;
    };
    float* h    = (float*)alloc((size_t)n * 64 * 4);
    float* q    = (float*)alloc((size_t)n * 64 * 4);
    __half* kvh = (__half*)alloc((size_t)n * 128 * 2);
    float* oacc = (float*)alloc((size_t)n * 64 * 4);
    int* deg    = (int*)alloc((size_t)n * 4);
    int* excl   = (int*)alloc((size_t)n * 4);
    int* bsum   = (int*)alloc(512 * 4);
    int* row    = (int*)alloc((size_t)(n + 1) * 4);
    int* cursor = (int*)alloc((size_t)n * 4);
    int2* ep    = (int2*)alloc((size_t)E * 8);
    int4* pk_in   = (int4*)alloc(4 * 128 * 16);
    int4* pk_skip = (int4*)alloc(3 * 8 * 128 * 16);
    int4* pk_qkv  = (int4*)alloc((size_t)3 * 24 * 128 * 16);
    float* gsum = (float*)alloc((NGRAPH * 64 * 2 + NGRAPH) * 4);
    unsigned int* gmax = (unsigned int*)(gsum + NGRAPH * 64);
    float* cnt  = gsum + NGRAPH * 128;

    int nb4 = (n + 3) / 4;
    int nb64 = (n + 63) / 64;
    int nbs = (n + 255) / 256;
    int ebs = (E + 255) / 256;

    k_cvt<<<25, 256, 0, stream>>>(in_W, W_skip, W_qkv, pk_in, pk_skip, pk_qkv);
    hipMemsetAsync(deg, 0, (size_t)n * 4, stream);
    k_hist<<<ebs, 256, 0, stream>>>(dst, deg, E);
    k_scan1<<<nbs, 256, 0, stream>>>(deg, excl, bsum, n);
    k_scan2<<<1, 512, 0, stream>>>(bsum, nbs);
    k_scan3<<<nbs, 256, 0, stream>>>(excl, bsum, row, cursor, n, E);
    k_scatter<<<ebs, 256, 0, stream>>>(src, dst, ea, cursor, ep, E);

    k_in_qkv<<<nb64, 256, 0, stream>>>(x, pk_in, in_b, in_lng, in_lnb,
                                       pk_qkv, b_qkv, h, q, kvh, n);

    for (int l = 0; l < LAYERS; l++) {
        k_attn<<<nb4, 256, 0, stream>>>(q, kvh, row, ep, W_edge + l * 64, oacc, n);
        if (l + 1 < LAYERS) {
            k_node_qkv<1><<<nb64, 256, 0, stream>>>(
                h, oacc, pk_skip + l * 8 * 128, b_skip + l * 64,
                W_beta + l * 192, ln_g + l * 64, ln_b + l * 64,
                pk_qkv + (size_t)(l + 1) * 24 * 128, b_qkv + (size_t)(l + 1) * 192,
                q, kvh, n);
        } else {
            k_node_qkv<0><<<nb64, 256, 0, stream>>>(
                h, oacc, pk_skip + l * 8 * 128, b_skip + l * 64,
                W_beta + l * 192, ln_g + l * 64, ln_b + l * 64,
                nullptr, nullptr, nullptr, nullptr, n);
        }
    }

    hipMemsetAsync(gsum, 0, (NGRAPH * 64 * 2 + NGRAPH) * 4, stream);
    int nwaves = 4096;
    int chunk = (n + nwaves - 1) / nwaves;
    k_pool3<<<nwaves / 4, 256, 0, stream>>>(h, batch, gsum, gmax, cnt, n, chunk);
    k_final<<<NGRAPH, 64, 0, stream>>>(gsum, gmax, cnt, r1_W, r1_b, r2_W, r2_b,
                                       r3_W, r3_b, (float*)d_out);
}